// Round 2
// baseline (234.189 us; speedup 1.0000x reference)
//
#include <hip/hip_runtime.h>
#include <hip/hip_bf16.h>
#include <math.h>

#define NN 768
#define DD 256
#define NHEAD 4
#define HDIM 64
#define TOPK 16

// ------------------------------------------------- row norms (float64 for topk)
__global__ __launch_bounds__(64) void k_norms(const float* __restrict__ x,
                                              double* __restrict__ nrm2_d,
                                              double* __restrict__ invn_d) {
    int n = blockIdx.x;
    int lane = threadIdx.x;
    const float* row = x + (size_t)n * DD;
    double s = 0.0;
    for (int i = lane; i < DD; i += 64) { double v = (double)row[i]; s += v * v; }
    for (int off = 32; off > 0; off >>= 1) s += __shfl_down(s, off);
    if (lane == 0) {
        nrm2_d[n] = s;
        double nv = sqrt(s);
        invn_d[n] = 1.0 / fmax(nv, 1e-12);
    }
}

// ------------------------------------------- edge features + edge MLP fused
// 32x32 pair tile per block; dot in fp64 (drives discrete top-k), rest fp32.
__global__ __launch_bounds__(256) void k_edge(const float* __restrict__ x,
                                              const double* __restrict__ nrm2_d,
                                              const double* __restrict__ invn_d,
                                              const float* __restrict__ e1_w,
                                              const float* __restrict__ e1_b,
                                              const float* __restrict__ e2_w,
                                              const float* __restrict__ e2_b,
                                              const float* __restrict__ gate_p,
                                              double* __restrict__ simd,
                                              float* __restrict__ biasv) {
    __shared__ float A[32][65];
    __shared__ float Bm[32][65];
    int n0 = blockIdx.y * 32, m0 = blockIdx.x * 32;
    int tid = threadIdx.x;
    int tx = tid & 31;   // local m
    int ty = tid >> 5;   // 0..7 (local n stride 8)
    double dot[4] = {0.0, 0.0, 0.0, 0.0};
    float sab[4] = {0.f, 0.f, 0.f, 0.f};
    float mab[4] = {0.f, 0.f, 0.f, 0.f};

    for (int d0 = 0; d0 < DD; d0 += 64) {
        #pragma unroll
        for (int it = 0; it < 8; ++it) {
            int l = tid + 256 * it;      // 0..2047
            int r = l >> 6, c = l & 63;
            A[r][c]  = x[(size_t)(n0 + r) * DD + d0 + c];
            Bm[r][c] = x[(size_t)(m0 + r) * DD + d0 + c];
        }
        __syncthreads();
        for (int d = 0; d < 64; ++d) {
            float bv = Bm[tx][d];
            double bvd = (double)bv;
            #pragma unroll
            for (int r = 0; r < 4; ++r) {
                float av = A[ty + 8 * r][d];
                float df = av - bv;
                float ad = fabsf(df);
                dot[r] += (double)av * bvd;
                sab[r] += ad;
                mab[r] = fmaxf(mab[r], ad);
            }
        }
        __syncthreads();
    }

    float gate = gate_p[0];
    #pragma unroll
    for (int r = 0; r < 4; ++r) {
        int n = n0 + ty + 8 * r;
        int m = m0 + tx;
        double s_d = dot[r] * invn_d[n] * invn_d[m];
        simd[(size_t)n * NN + m] = s_d;
        double l2sq = fmax(nrm2_d[n] + nrm2_d[m] - 2.0 * dot[r], 0.0);
        float ef0 = (float)s_d;
        float ef1 = (float)(sqrt(l2sq) * (1.0 / 16.0));  // / sqrt(256)
        float ef2 = sab[r] * (1.f / 256.f);
        float ef3 = mab[r];
        float hbuf[8];
        #pragma unroll
        for (int j = 0; j < 8; ++j) {
            float hv = e1_b[j] + ef0 * e1_w[0 * 8 + j] + ef1 * e1_w[1 * 8 + j]
                     + ef2 * e1_w[2 * 8 + j] + ef3 * e1_w[3 * 8 + j];
            hbuf[j] = fmaxf(hv, 0.f);
        }
        #pragma unroll
        for (int hh = 0; hh < NHEAD; ++hh) {
            float bb = e2_b[hh];
            #pragma unroll
            for (int j = 0; j < 8; ++j) bb += hbuf[j] * e2_w[j * 4 + hh];
            biasv[((size_t)hh * NN + n) * NN + m] = gate * bb;
        }
    }
}

// -------------------------------------------------- top-k (K=16) + adjacency
__global__ __launch_bounds__(256) void k_topk(const double* __restrict__ simd,
                                              unsigned char* __restrict__ adj) {
    int n = blockIdx.x;
    __shared__ double row[NN];
    __shared__ double rv[256];
    __shared__ int    ri[256];
    int tid = threadIdx.x;
    // diagonal excluded at load time (no write-after-write race)
    for (int m = tid; m < NN; m += 256)
        row[m] = (m == n) ? -INFINITY : simd[(size_t)n * NN + m];
    if (tid == 0) adj[(size_t)n * NN + n] = 1;   // self loop
    __syncthreads();
    for (int itr = 0; itr < TOPK; ++itr) {
        double bv = -INFINITY; int bi = NN;
        for (int m = tid; m < NN; m += 256) {
            double v = row[m];
            if (v > bv) { bv = v; bi = m; }
        }
        rv[tid] = bv; ri[tid] = bi;
        __syncthreads();
        for (int s = 128; s > 0; s >>= 1) {
            if (tid < s) {
                double ov = rv[tid + s]; int oi = ri[tid + s];
                if (ov > rv[tid] || (ov == rv[tid] && oi < ri[tid])) {
                    rv[tid] = ov; ri[tid] = oi;
                }
            }
            __syncthreads();
        }
        if (tid == 0) {
            int best = ri[0];
            row[best] = -INFINITY;
            adj[(size_t)n * NN + best] = 1;
            adj[(size_t)best * NN + n] = 1;
        }
        __syncthreads();
    }
}

// ----------------------------------------------------------------- QKV GEMM
__global__ __launch_bounds__(256) void k_qkv(const float* __restrict__ x,
                                             const float* __restrict__ W,
                                             const float* __restrict__ bias,
                                             float* __restrict__ q,
                                             float* __restrict__ k,
                                             float* __restrict__ v) {
    __shared__ float As[32][33];
    __shared__ float Bs[32][33];
    int n0 = blockIdx.y * 32, c0 = blockIdx.x * 32;
    int tid = threadIdx.x, tx = tid & 31, ty = tid >> 5;
    float acc[4] = {0.f, 0.f, 0.f, 0.f};
    for (int k0 = 0; k0 < DD; k0 += 32) {
        #pragma unroll
        for (int it = 0; it < 4; ++it) {
            int l = tid + 256 * it; int r = l >> 5, c = l & 31;
            As[r][c] = x[(size_t)(n0 + r) * DD + k0 + c];
            Bs[r][c] = W[(size_t)(k0 + r) * (3 * DD) + c0 + c];
        }
        __syncthreads();
        #pragma unroll
        for (int kk = 0; kk < 32; ++kk) {
            float bv = Bs[kk][tx];
            #pragma unroll
            for (int r = 0; r < 4; ++r) acc[r] += As[ty + 8 * r][kk] * bv;
        }
        __syncthreads();
    }
    int c = c0 + tx;
    int h = c / 192, rem = c % 192, hd = rem / 3, s = rem % 3;
    float* dst = (s == 0) ? q : (s == 1) ? k : v;
    float bb = bias[c];
    #pragma unroll
    for (int r = 0; r < 4; ++r) {
        int n = n0 + ty + 8 * r;
        dst[((size_t)h * NN + n) * HDIM + hd] = acc[r] + bb;
    }
}

// -------------------------------------------------- attention per (n, head)
__global__ __launch_bounds__(256) void k_attn(const float* __restrict__ q,
                                              const float* __restrict__ k,
                                              const float* __restrict__ v,
                                              const float* __restrict__ biasv,
                                              const unsigned char* __restrict__ adj,
                                              float* __restrict__ ctx) {
    int n = blockIdx.x, h = blockIdx.y;
    __shared__ float qv[HDIM];
    __shared__ float lg[NN];
    __shared__ float red[256];
    int tid = threadIdx.x;
    if (tid < HDIM) qv[tid] = q[((size_t)h * NN + n) * HDIM + tid];
    __syncthreads();

    float lmax = -INFINITY;
    for (int m = tid; m < NN; m += 256) {
        const float* kr = k + ((size_t)h * NN + m) * HDIM;
        float dotv = 0.f;
        #pragma unroll
        for (int dd = 0; dd < HDIM; ++dd) dotv += qv[dd] * kr[dd];
        float lv = -INFINITY;
        if (adj[(size_t)n * NN + m])
            lv = dotv * 0.125f + biasv[((size_t)h * NN + n) * NN + m];
        lg[m] = lv;
        lmax = fmaxf(lmax, lv);
    }
    red[tid] = lmax; __syncthreads();
    for (int s = 128; s > 0; s >>= 1) {
        if (tid < s) red[tid] = fmaxf(red[tid], red[tid + s]);
        __syncthreads();
    }
    lmax = red[0];
    __syncthreads();

    float lsum = 0.f;
    for (int m = tid; m < NN; m += 256) {
        float e = expf(lg[m] - lmax);
        lg[m] = e;
        lsum += e;
    }
    red[tid] = lsum; __syncthreads();
    for (int s = 128; s > 0; s >>= 1) {
        if (tid < s) red[tid] += red[tid + s];
        __syncthreads();
    }
    float inv = 1.f / red[0];
    __syncthreads();

    int hd = tid & 63, chunk = tid >> 6;    // 4 chunks x 192 m's
    float acc = 0.f;
    for (int m = chunk * 192; m < (chunk + 1) * 192; ++m)
        acc += lg[m] * v[((size_t)h * NN + m) * HDIM + hd];
    red[tid] = acc; __syncthreads();
    if (tid < 64) {
        float r = red[tid] + red[tid + 64] + red[tid + 128] + red[tid + 192];
        ctx[(size_t)n * DD + h * HDIM + tid] = r * inv;
    }
}

// ------------------------------------------------------------- generic GEMM
template<int KD, bool CONCAT, bool RESID>
__global__ __launch_bounds__(256) void k_gemm(const float* __restrict__ A,
                                              const float* __restrict__ A2,
                                              const float* __restrict__ B,
                                              const float* __restrict__ bias,
                                              const float* __restrict__ resid,
                                              float* __restrict__ out,
                                              int ncols) {
    __shared__ float As[32][33];
    __shared__ float Bs[32][33];
    int n0 = blockIdx.y * 32, c0 = blockIdx.x * 32;
    int tid = threadIdx.x, tx = tid & 31, ty = tid >> 5;
    float acc[4] = {0.f, 0.f, 0.f, 0.f};
    for (int k0 = 0; k0 < KD; k0 += 32) {
        const float* Asrc; int koff, lda;
        if (CONCAT) {
            if (k0 < 256) { Asrc = A;  koff = k0;       lda = 256; }
            else          { Asrc = A2; koff = k0 - 256; lda = 256; }
        } else { Asrc = A; koff = k0; lda = KD; }
        #pragma unroll
        for (int it = 0; it < 4; ++it) {
            int l = tid + 256 * it; int r = l >> 5, c = l & 31;
            As[r][c] = Asrc[(size_t)(n0 + r) * lda + koff + c];
            Bs[r][c] = B[(size_t)(k0 + r) * ncols + c0 + c];
        }
        __syncthreads();
        #pragma unroll
        for (int kk = 0; kk < 32; ++kk) {
            float bv = Bs[kk][tx];
            #pragma unroll
            for (int r = 0; r < 4; ++r) acc[r] += As[ty + 8 * r][kk] * bv;
        }
        __syncthreads();
    }
    int c = c0 + tx;
    float bb = bias[c];
    #pragma unroll
    for (int r = 0; r < 4; ++r) {
        int n = n0 + ty + 8 * r;
        float val = acc[r] + bb;
        if (RESID) val += resid[(size_t)n * ncols + c];
        out[(size_t)n * ncols + c] = val;
    }
}

// -------------------------------------------------- LayerNorm + exact GELU
__global__ __launch_bounds__(256) void k_ln_gelu(float* __restrict__ y,
                                                 const float* __restrict__ g,
                                                 const float* __restrict__ b) {
    int n = blockIdx.x;
    int tid = threadIdx.x;
    float* row = y + (size_t)n * 512;
    __shared__ float red[256];
    float v0 = row[tid], v1 = row[tid + 256];

    red[tid] = v0 + v1; __syncthreads();
    for (int s = 128; s > 0; s >>= 1) {
        if (tid < s) red[tid] += red[tid + s];
        __syncthreads();
    }
    float mu = red[0] * (1.f / 512.f);
    __syncthreads();

    float d0 = v0 - mu, d1 = v1 - mu;
    red[tid] = d0 * d0 + d1 * d1; __syncthreads();
    for (int s = 128; s > 0; s >>= 1) {
        if (tid < s) red[tid] += red[tid + s];
        __syncthreads();
    }
    float var = red[0] * (1.f / 512.f);
    float rstd = 1.f / sqrtf(var + 1e-5f);

    float z0 = d0 * rstd * g[tid] + b[tid];
    float z1 = d1 * rstd * g[tid + 256] + b[tid + 256];
    row[tid]       = 0.5f * z0 * (1.f + erff(z0 * 0.70710678118654752f));
    row[tid + 256] = 0.5f * z1 * (1.f + erff(z1 * 0.70710678118654752f));
}

// --------------------------------------------------------------------- host
extern "C" void kernel_launch(void* const* d_in, const int* in_sizes, int n_in,
                              void* d_out, int out_size, void* d_ws, size_t ws_size,
                              hipStream_t stream) {
    const float* x       = (const float*)d_in[0];
    const float* Wqkv_w  = (const float*)d_in[1];
    const float* Wqkv_b  = (const float*)d_in[2];
    const float* out_w   = (const float*)d_in[3];
    const float* out_b   = (const float*)d_in[4];
    const float* ffn1_w  = (const float*)d_in[5];
    const float* ffn1_b  = (const float*)d_in[6];
    const float* ln_g    = (const float*)d_in[7];
    const float* ln_b    = (const float*)d_in[8];
    const float* ffn2_w  = (const float*)d_in[9];
    const float* ffn2_b  = (const float*)d_in[10];
    const float* e1_w    = (const float*)d_in[11];
    const float* e1_b    = (const float*)d_in[12];
    const float* e2_w    = (const float*)d_in[13];
    const float* e2_b    = (const float*)d_in[14];
    const float* gate    = (const float*)d_in[15];

    char* base = (char*)d_ws;
    double* simd   = (double*)base;           base += (size_t)NN * NN * 8;     // 4.72 MB
    double* nrm2_d = (double*)base;           base += NN * 8;
    double* invn_d = (double*)base;           base += NN * 8;
    float* biasv   = (float*)base;            base += (size_t)NHEAD * NN * NN * 4; // 9.44 MB
    unsigned char* adj = (unsigned char*)base; base += (size_t)NN * NN;        // 0.59 MB
    float* qb      = (float*)base;            base += (size_t)NN * DD * 4;
    float* kb      = (float*)base;            base += (size_t)NN * DD * 4;
    float* vb      = (float*)base;            base += (size_t)NN * DD * 4;
    float* ctx     = (float*)base;            base += (size_t)NN * DD * 4;
    float* msg     = (float*)base;            base += (size_t)NN * DD * 4;
    float* yb      = (float*)base;            base += (size_t)NN * 512 * 4;

    hipMemsetAsync(adj, 0, (size_t)NN * NN, stream);

    k_norms<<<NN, 64, 0, stream>>>(x, nrm2_d, invn_d);

    k_edge<<<dim3(NN / 32, NN / 32), 256, 0, stream>>>(
        x, nrm2_d, invn_d, e1_w, e1_b, e2_w, e2_b, gate, simd, biasv);

    k_topk<<<NN, 256, 0, stream>>>(simd, adj);

    k_qkv<<<dim3((3 * DD) / 32, NN / 32), 256, 0, stream>>>(
        x, Wqkv_w, Wqkv_b, qb, kb, vb);

    k_attn<<<dim3(NN, NHEAD), 256, 0, stream>>>(qb, kb, vb, biasv, adj, ctx);

    // msg = ctx @ out_w + out_b
    k_gemm<256, false, false><<<dim3(DD / 32, NN / 32), 256, 0, stream>>>(
        ctx, nullptr, out_w, out_b, nullptr, msg, DD);

    // y = [x, msg] @ ffn1_w + ffn1_b
    k_gemm<512, true, false><<<dim3(512 / 32, NN / 32), 256, 0, stream>>>(
        x, msg, ffn1_w, ffn1_b, nullptr, yb, 512);

    k_ln_gelu<<<NN, 256, 0, stream>>>(yb, ln_g, ln_b);

    // out = x + y @ ffn2_w + ffn2_b
    k_gemm<512, false, true><<<dim3(DD / 32, NN / 32), 256, 0, stream>>>(
        yb, nullptr, ffn2_w, ffn2_b, x, (float*)d_out, DD);
}

// Round 3
// 175.377 us; speedup vs baseline: 1.3353x; 1.3353x over previous
//
#include <hip/hip_runtime.h>
#include <hip/hip_bf16.h>
#include <math.h>

#define NN 768
#define DD 256
#define NHEAD 4
#define HDIM 64
#define TOPK 16

// ------------------------------------------------- row norms (fp64, for topk)
__global__ __launch_bounds__(64) void k_norms(const float* __restrict__ x,
                                              double* __restrict__ nrm2_d,
                                              double* __restrict__ invn_d) {
    int n = blockIdx.x;
    int lane = threadIdx.x;
    const float* row = x + (size_t)n * DD;
    double s = 0.0;
    for (int i = lane; i < DD; i += 64) { double v = (double)row[i]; s += v * v; }
    for (int off = 32; off > 0; off >>= 1) s += __shfl_down(s, off);
    if (lane == 0) {
        nrm2_d[n] = s;
        invn_d[n] = 1.0 / fmax(sqrt(s), 1e-12);
    }
}

// ---------------------------------------------- dense fp64 similarity matrix
// 32x32 pair tile; dot only (edge features moved to sparse kernel).
__global__ __launch_bounds__(256) void k_sim(const float* __restrict__ x,
                                             const double* __restrict__ invn_d,
                                             double* __restrict__ simd) {
    __shared__ float A[32][68];
    __shared__ float Bm[32][68];
    int n0 = blockIdx.y * 32, m0 = blockIdx.x * 32;
    int tid = threadIdx.x;
    int tx = tid & 31;   // local m
    int ty = tid >> 5;   // 0..7 (local n stride 8)
    double dot[4] = {0.0, 0.0, 0.0, 0.0};

    for (int d0 = 0; d0 < DD; d0 += 64) {
        #pragma unroll
        for (int it = 0; it < 8; ++it) {
            int l = tid + 256 * it;
            int r = l >> 6, c = l & 63;
            A[r][c]  = x[(size_t)(n0 + r) * DD + d0 + c];
            Bm[r][c] = x[(size_t)(m0 + r) * DD + d0 + c];
        }
        __syncthreads();
        for (int d = 0; d < 64; d += 4) {
            float4 b4 = *(const float4*)&Bm[tx][d];
            #pragma unroll
            for (int r = 0; r < 4; ++r) {
                float4 a4 = *(const float4*)&A[ty + 8 * r][d];
                dot[r] += (double)a4.x * (double)b4.x + (double)a4.y * (double)b4.y
                        + (double)a4.z * (double)b4.z + (double)a4.w * (double)b4.w;
            }
        }
        __syncthreads();
    }
    double in_n[4];
    #pragma unroll
    for (int r = 0; r < 4; ++r) in_n[r] = invn_d[n0 + ty + 8 * r];
    double in_m = invn_d[m0 + tx];
    #pragma unroll
    for (int r = 0; r < 4; ++r)
        simd[(size_t)(n0 + ty + 8 * r) * NN + m0 + tx] = dot[r] * in_n[r] * in_m;
}

// -------------------------------------------------- top-k (K=16) + adjacency
__global__ __launch_bounds__(256) void k_topk(const double* __restrict__ simd,
                                              unsigned char* __restrict__ adj) {
    int n = blockIdx.x;
    __shared__ double row[NN];
    __shared__ double wmax[4];
    __shared__ int    widx[4];
    int tid = threadIdx.x;
    int wid = tid >> 6, lane = tid & 63;
    for (int m = tid; m < NN; m += 256)
        row[m] = (m == n) ? -INFINITY : simd[(size_t)n * NN + m];
    if (tid == 0) adj[(size_t)n * NN + n] = 1;
    __syncthreads();
    for (int itr = 0; itr < TOPK; ++itr) {
        double bv = -INFINITY; int bi = NN;
        for (int m = tid; m < NN; m += 256) {
            double v = row[m];
            if (v > bv) { bv = v; bi = m; }
        }
        for (int off = 32; off > 0; off >>= 1) {
            double ov = __shfl_down(bv, off);
            int    oi = __shfl_down(bi, off);
            if (ov > bv || (ov == bv && oi < bi)) { bv = ov; bi = oi; }
        }
        if (lane == 0) { wmax[wid] = bv; widx[wid] = bi; }
        __syncthreads();
        if (tid == 0) {
            double fv = wmax[0]; int fi = widx[0];
            #pragma unroll
            for (int w = 1; w < 4; ++w) {
                if (wmax[w] > fv || (wmax[w] == fv && widx[w] < fi)) {
                    fv = wmax[w]; fi = widx[w];
                }
            }
            row[fi] = -INFINITY;
            adj[(size_t)n * NN + fi] = 1;
            adj[(size_t)fi * NN + n] = 1;
        }
        __syncthreads();
    }
}

// ------------------------------------- compact neighbor lists (ordered scan)
__global__ __launch_bounds__(256) void k_nbr(const unsigned char* __restrict__ adj,
                                             unsigned short* __restrict__ nbr_idx,
                                             int* __restrict__ nbr_cnt) {
    int n = blockIdx.x;
    int tid = threadIdx.x;
    __shared__ int cnts[256];
    int local[3]; int c = 0;
    #pragma unroll
    for (int i = 0; i < 3; ++i) {
        int m = 3 * tid + i;
        if (adj[(size_t)n * NN + m]) local[c++] = m;
    }
    cnts[tid] = c;
    __syncthreads();
    for (int off = 1; off < 256; off <<= 1) {
        int v = (tid >= off) ? cnts[tid - off] : 0;
        __syncthreads();
        cnts[tid] += v;
        __syncthreads();
    }
    int start = cnts[tid] - c;
    for (int i = 0; i < c; ++i)
        nbr_idx[(size_t)n * NN + start + i] = (unsigned short)local[i];
    if (tid == 255) nbr_cnt[n] = cnts[255];
}

// ------------------------- sparse edge features + edge MLP (neighbors only)
__global__ __launch_bounds__(256) void k_edge_sp(const float* __restrict__ x,
                                                 const double* __restrict__ nrm2_d,
                                                 const double* __restrict__ simd,
                                                 const unsigned short* __restrict__ nbr_idx,
                                                 const int* __restrict__ nbr_cnt,
                                                 const float* __restrict__ e1_w,
                                                 const float* __restrict__ e1_b,
                                                 const float* __restrict__ e2_w,
                                                 const float* __restrict__ e2_b,
                                                 const float* __restrict__ gate_p,
                                                 float* __restrict__ bias_sp) {
    int n = blockIdx.x;
    int tid = threadIdx.x;
    int w = tid >> 6, l = tid & 63;
    int cnt = nbr_cnt[n];
    float xa[4];
    #pragma unroll
    for (int i = 0; i < 4; ++i) xa[i] = x[(size_t)n * DD + l + 64 * i];
    double nrm2n = nrm2_d[n];
    double nrmn  = sqrt(nrm2n);
    float gate = gate_p[0];

    for (int j = w; j < cnt; j += 4) {
        int m = nbr_idx[(size_t)n * NN + j];
        float sab = 0.f, mab = 0.f;
        #pragma unroll
        for (int i = 0; i < 4; ++i) {
            float xb = x[(size_t)m * DD + l + 64 * i];
            float ad = fabsf(xa[i] - xb);
            sab += ad;
            mab = fmaxf(mab, ad);
        }
        for (int off = 32; off > 0; off >>= 1) {
            sab += __shfl_xor(sab, off);
            mab = fmaxf(mab, __shfl_xor(mab, off));
        }
        if (l == 0) {
            double s_d   = simd[(size_t)n * NN + m];
            double nrm2m = nrm2_d[m];
            double dot   = s_d * nrmn * sqrt(nrm2m);
            double l2sq  = fmax(nrm2n + nrm2m - 2.0 * dot, 0.0);
            float ef0 = (float)s_d;
            float ef1 = (float)(sqrt(l2sq) * (1.0 / 16.0));
            float ef2 = sab * (1.f / 256.f);
            float ef3 = mab;
            float hbuf[8];
            #pragma unroll
            for (int jj = 0; jj < 8; ++jj) {
                float hv = e1_b[jj] + ef0 * e1_w[0 * 8 + jj] + ef1 * e1_w[1 * 8 + jj]
                         + ef2 * e1_w[2 * 8 + jj] + ef3 * e1_w[3 * 8 + jj];
                hbuf[jj] = fmaxf(hv, 0.f);
            }
            #pragma unroll
            for (int hh = 0; hh < NHEAD; ++hh) {
                float bb = e2_b[hh];
                #pragma unroll
                for (int jj = 0; jj < 8; ++jj) bb += hbuf[jj] * e2_w[jj * 4 + hh];
                bias_sp[((size_t)hh * NN + n) * NN + j] = gate * bb;
            }
        }
    }
}

// ------------------------------------- sparse attention: one block per row n
__global__ __launch_bounds__(256) void k_attn_sp(const float* __restrict__ q,
                                                 const float* __restrict__ k,
                                                 const float* __restrict__ v,
                                                 const float* __restrict__ bias_sp,
                                                 const unsigned short* __restrict__ nbr_idx,
                                                 const int* __restrict__ nbr_cnt,
                                                 float* __restrict__ ctx) {
    int n = blockIdx.x;
    int tid = threadIdx.x;
    int h = tid >> 6, l = tid & 63;
    __shared__ unsigned short idxs[NN];
    __shared__ float w_sh[NHEAD][NN];
    __shared__ float qsh[NHEAD][HDIM];
    int cnt = nbr_cnt[n];
    for (int j = tid; j < cnt; j += 256) idxs[j] = nbr_idx[(size_t)n * NN + j];
    qsh[h][l] = q[((size_t)h * NN + n) * HDIM + l];
    __syncthreads();

    // logits for my lane's neighbor slots
    float lmax = -INFINITY;
    for (int j = l; j < cnt; j += 64) {
        int m = idxs[j];
        const float4* kr = (const float4*)(k + ((size_t)h * NN + m) * HDIM);
        float dotv = 0.f;
        #pragma unroll
        for (int d4 = 0; d4 < HDIM / 4; ++d4) {
            float4 kv = kr[d4];
            dotv += qsh[h][4 * d4 + 0] * kv.x + qsh[h][4 * d4 + 1] * kv.y
                  + qsh[h][4 * d4 + 2] * kv.z + qsh[h][4 * d4 + 3] * kv.w;
        }
        w_sh[h][j] = dotv * 0.125f + bias_sp[((size_t)h * NN + n) * NN + j];
        lmax = fmaxf(lmax, w_sh[h][j]);
    }
    for (int off = 32; off > 0; off >>= 1)
        lmax = fmaxf(lmax, __shfl_xor(lmax, off));

    float lsum = 0.f;
    for (int j = l; j < cnt; j += 64) {
        float e = expf(w_sh[h][j] - lmax);
        w_sh[h][j] = e;
        lsum += e;
    }
    for (int off = 32; off > 0; off >>= 1) lsum += __shfl_xor(lsum, off);
    float inv = 1.f / lsum;
    __syncthreads();   // w_sh fully written before cross-lane PV reads

    float acc = 0.f;
    for (int j = 0; j < cnt; ++j)
        acc += w_sh[h][j] * v[((size_t)h * NN + idxs[j]) * HDIM + l];
    ctx[(size_t)n * DD + h * HDIM + l] = acc * inv;
}

// ----------------------------- 64x64 tiled GEMM, 4x4 micro-tile per thread
// MODE 0: out = A@B + bias          MODE 1: out = A@B + bias + resid
// MODE 2: qkv scatter into q/k/v
template<int KD, int MODE, bool CONCAT>
__global__ __launch_bounds__(256) void k_gemm64(const float* __restrict__ A,
                                                const float* __restrict__ A2,
                                                const float* __restrict__ B,
                                                const float* __restrict__ bias,
                                                const float* __restrict__ resid,
                                                float* __restrict__ out,
                                                float* __restrict__ q,
                                                float* __restrict__ k,
                                                float* __restrict__ v,
                                                int ncols) {
    __shared__ float As[16][68];
    __shared__ float Bs[16][68];
    int n0 = blockIdx.y * 64, c0 = blockIdx.x * 64;
    int tid = threadIdx.x;
    int tx = tid & 15, ty = tid >> 4;
    float acc[4][4] = {};

    int arow = tid >> 2, kq = tid & 3;       // A-load mapping
    int bk = tid >> 4, bc4 = (tid & 15) * 4; // B-load mapping

    for (int k0 = 0; k0 < KD; k0 += 16) {
        const float* Asrc = A; int koff = k0; int lda = KD;
        if (CONCAT) {
            if (k0 < 256) { Asrc = A;  koff = k0;       lda = 256; }
            else          { Asrc = A2; koff = k0 - 256; lda = 256; }
        }
        float4 av = *(const float4*)&Asrc[(size_t)(n0 + arow) * lda + koff + kq * 4];
        float4 bv = *(const float4*)&B[(size_t)(k0 + bk) * ncols + c0 + bc4];
        As[kq * 4 + 0][arow] = av.x;
        As[kq * 4 + 1][arow] = av.y;
        As[kq * 4 + 2][arow] = av.z;
        As[kq * 4 + 3][arow] = av.w;
        *(float4*)&Bs[bk][bc4] = bv;
        __syncthreads();
        #pragma unroll
        for (int kk = 0; kk < 16; ++kk) {
            float4 a4 = *(const float4*)&As[kk][ty * 4];
            float4 b4 = *(const float4*)&Bs[kk][tx * 4];
            float aa[4] = {a4.x, a4.y, a4.z, a4.w};
            float bb[4] = {b4.x, b4.y, b4.z, b4.w};
            #pragma unroll
            for (int i = 0; i < 4; ++i)
                #pragma unroll
                for (int jj = 0; jj < 4; ++jj)
                    acc[i][jj] += aa[i] * bb[jj];
        }
        __syncthreads();
    }

    if (MODE == 2) {
        #pragma unroll
        for (int jj = 0; jj < 4; ++jj) {
            int c = c0 + tx * 4 + jj;
            int hh = c / 192, rem = c % 192, hd = rem / 3, s = rem % 3;
            float* dst = (s == 0) ? q : (s == 1) ? k : v;
            float bb = bias[c];
            #pragma unroll
            for (int i = 0; i < 4; ++i) {
                int n = n0 + ty * 4 + i;
                dst[((size_t)hh * NN + n) * HDIM + hd] = acc[i][jj] + bb;
            }
        }
    } else {
        float4 b4 = *(const float4*)&bias[c0 + tx * 4];
        float bb[4] = {b4.x, b4.y, b4.z, b4.w};
        #pragma unroll
        for (int i = 0; i < 4; ++i) {
            int n = n0 + ty * 4 + i;
            float4 o;
            o.x = acc[i][0] + bb[0];
            o.y = acc[i][1] + bb[1];
            o.z = acc[i][2] + bb[2];
            o.w = acc[i][3] + bb[3];
            if (MODE == 1) {
                float4 r4 = *(const float4*)&resid[(size_t)n * ncols + c0 + tx * 4];
                o.x += r4.x; o.y += r4.y; o.z += r4.z; o.w += r4.w;
            }
            *(float4*)&out[(size_t)n * ncols + c0 + tx * 4] = o;
        }
    }
}

// -------------------------------------------------- LayerNorm + exact GELU
__global__ __launch_bounds__(256) void k_ln_gelu(float* __restrict__ y,
                                                 const float* __restrict__ g,
                                                 const float* __restrict__ b) {
    int n = blockIdx.x;
    int tid = threadIdx.x;
    float* row = y + (size_t)n * 512;
    __shared__ float red[256];
    float v0 = row[tid], v1 = row[tid + 256];

    red[tid] = v0 + v1; __syncthreads();
    for (int s = 128; s > 0; s >>= 1) {
        if (tid < s) red[tid] += red[tid + s];
        __syncthreads();
    }
    float mu = red[0] * (1.f / 512.f);
    __syncthreads();

    float d0 = v0 - mu, d1 = v1 - mu;
    red[tid] = d0 * d0 + d1 * d1; __syncthreads();
    for (int s = 128; s > 0; s >>= 1) {
        if (tid < s) red[tid] += red[tid + s];
        __syncthreads();
    }
    float var = red[0] * (1.f / 512.f);
    float rstd = 1.f / sqrtf(var + 1e-5f);

    float z0 = d0 * rstd * g[tid] + b[tid];
    float z1 = d1 * rstd * g[tid + 256] + b[tid + 256];
    row[tid]       = 0.5f * z0 * (1.f + erff(z0 * 0.70710678118654752f));
    row[tid + 256] = 0.5f * z1 * (1.f + erff(z1 * 0.70710678118654752f));
}

// --------------------------------------------------------------------- host
extern "C" void kernel_launch(void* const* d_in, const int* in_sizes, int n_in,
                              void* d_out, int out_size, void* d_ws, size_t ws_size,
                              hipStream_t stream) {
    const float* x       = (const float*)d_in[0];
    const float* Wqkv_w  = (const float*)d_in[1];
    const float* Wqkv_b  = (const float*)d_in[2];
    const float* out_w   = (const float*)d_in[3];
    const float* out_b   = (const float*)d_in[4];
    const float* ffn1_w  = (const float*)d_in[5];
    const float* ffn1_b  = (const float*)d_in[6];
    const float* ln_g    = (const float*)d_in[7];
    const float* ln_b    = (const float*)d_in[8];
    const float* ffn2_w  = (const float*)d_in[9];
    const float* ffn2_b  = (const float*)d_in[10];
    const float* e1_w    = (const float*)d_in[11];
    const float* e1_b    = (const float*)d_in[12];
    const float* e2_w    = (const float*)d_in[13];
    const float* e2_b    = (const float*)d_in[14];
    const float* gate    = (const float*)d_in[15];

    char* base = (char*)d_ws;
    double* simd   = (double*)base;            base += (size_t)NN * NN * 8;
    double* nrm2_d = (double*)base;            base += NN * 8;
    double* invn_d = (double*)base;            base += NN * 8;
    float* bias_sp = (float*)base;             base += (size_t)NHEAD * NN * NN * 4;
    float* qb      = (float*)base;             base += (size_t)NN * DD * 4;
    float* kb      = (float*)base;             base += (size_t)NN * DD * 4;
    float* vb      = (float*)base;             base += (size_t)NN * DD * 4;
    float* ctx     = (float*)base;             base += (size_t)NN * DD * 4;
    float* msg     = (float*)base;             base += (size_t)NN * DD * 4;
    float* yb      = (float*)base;             base += (size_t)NN * 512 * 4;
    int* nbr_cnt   = (int*)base;               base += NN * 4;
    unsigned short* nbr_idx = (unsigned short*)base; base += (size_t)NN * NN * 2;
    unsigned char* adj = (unsigned char*)base;  base += (size_t)NN * NN;

    hipMemsetAsync(adj, 0, (size_t)NN * NN, stream);

    k_norms<<<NN, 64, 0, stream>>>(x, nrm2_d, invn_d);

    k_sim<<<dim3(NN / 32, NN / 32), 256, 0, stream>>>(x, invn_d, simd);

    k_topk<<<NN, 256, 0, stream>>>(simd, adj);

    k_nbr<<<NN, 256, 0, stream>>>(adj, nbr_idx, nbr_cnt);

    k_edge_sp<<<NN, 256, 0, stream>>>(x, nrm2_d, simd, nbr_idx, nbr_cnt,
                                      e1_w, e1_b, e2_w, e2_b, gate, bias_sp);

    k_gemm64<DD, 2, false><<<dim3(768 / 64, NN / 64), 256, 0, stream>>>(
        x, nullptr, Wqkv_w, Wqkv_b, nullptr, nullptr, qb, kb, vb, 3 * DD);

    k_attn_sp<<<NN, 256, 0, stream>>>(qb, kb, vb, bias_sp, nbr_idx, nbr_cnt, ctx);

    // msg = ctx @ out_w + out_b
    k_gemm64<DD, 0, false><<<dim3(DD / 64, NN / 64), 256, 0, stream>>>(
        ctx, nullptr, out_w, out_b, nullptr, msg, nullptr, nullptr, nullptr, DD);

    // y = [x, msg] @ ffn1_w + ffn1_b
    k_gemm64<512, 0, true><<<dim3(512 / 64, NN / 64), 256, 0, stream>>>(
        x, msg, ffn1_w, ffn1_b, nullptr, yb, nullptr, nullptr, nullptr, 512);

    k_ln_gelu<<<NN, 256, 0, stream>>>(yb, ln_g, ln_b);

    // out = x + y @ ffn2_w + ffn2_b
    k_gemm64<512, 1, false><<<dim3(DD / 64, NN / 64), 256, 0, stream>>>(
        yb, nullptr, ffn2_w, ffn2_b, x, (float*)d_out, nullptr, nullptr, nullptr, DD);
}

// Round 4
// 143.206 us; speedup vs baseline: 1.6353x; 1.2246x over previous
//
#include <hip/hip_runtime.h>
#include <hip/hip_bf16.h>
#include <math.h>

#define NN 768
#define DD 256
#define NHEAD 4
#define HDIM 64
#define TOPK 16

typedef __attribute__((ext_vector_type(8))) short short8;
typedef __attribute__((ext_vector_type(4))) float f32x4;

__device__ __forceinline__ unsigned short f2bf(float f) {
    unsigned u = __float_as_uint(f);
    unsigned r = u + 0x7fffu + ((u >> 16) & 1u);
    return (unsigned short)(r >> 16);
}
__device__ __forceinline__ float bf2f(unsigned short s) {
    return __uint_as_float(((unsigned)s) << 16);
}

// ---------------- MFMA layout probe: A=I(16) (K=32), asymmetric B, D==B? ----
__device__ __forceinline__ float probe_bval(int k, int c) {
    return (float)(((k * 7 + c * 3) & 15) - 8) * 0.125f;
}
__global__ __launch_bounds__(64) void k_probe(float* __restrict__ flag) {
    int l = threadIdx.x;
    int fr = l & 15, fg = l >> 4;
    short8 a, b;
    #pragma unroll
    for (int e = 0; e < 8; ++e) {
        int kk = fg * 8 + e;
        a[e] = (short)((fr == kk) ? f2bf(1.0f) : 0);
        b[e] = (short)f2bf(probe_bval(kk, fr));
    }
    f32x4 z = {0.f, 0.f, 0.f, 0.f};
    f32x4 d = __builtin_amdgcn_mfma_f32_16x16x32_bf16(a, b, z, 0, 0, 0);
    bool ok = true;
    #pragma unroll
    for (int r = 0; r < 4; ++r) {
        float exp = probe_bval(fg * 4 + r, fr);
        ok = ok && (fabsf(d[r] - exp) < 1e-5f);
    }
    unsigned long long good = __ballot(ok ? 1 : 0);
    if (l == 0) flag[0] = (good == 0xFFFFFFFFFFFFFFFFull) ? 1.f : 0.f;
}

// ------------------------------- row norms (fp64 for topk) + x -> bf16 copy
__global__ __launch_bounds__(64) void k_norms(const float* __restrict__ x,
                                              double* __restrict__ nrm2_d,
                                              double* __restrict__ invn_d,
                                              unsigned short* __restrict__ xb) {
    int n = blockIdx.x;
    int lane = threadIdx.x;
    const float* row = x + (size_t)n * DD;
    double s = 0.0;
    #pragma unroll
    for (int i = 0; i < 4; ++i) {
        float v = row[lane + 64 * i];
        xb[(size_t)n * DD + lane + 64 * i] = f2bf(v);
        s += (double)v * (double)v;
    }
    for (int off = 32; off > 0; off >>= 1) s += __shfl_down(s, off);
    if (lane == 0) {
        nrm2_d[n] = s;
        invn_d[n] = 1.0 / fmax(sqrt(s), 1e-12);
    }
}

// ---------------------- dense fp64 similarity, upper-triangle blocks only
__global__ __launch_bounds__(256) void k_sim(const float* __restrict__ x,
                                             const double* __restrict__ invn_d,
                                             double* __restrict__ simd) {
    if (blockIdx.x < blockIdx.y) return;   // keep m0 >= n0, mirror writes
    __shared__ float A[32][68];
    __shared__ float Bm[32][68];
    int n0 = blockIdx.y * 32, m0 = blockIdx.x * 32;
    int tid = threadIdx.x;
    int tx = tid & 31, ty = tid >> 5;
    double dot[4] = {0.0, 0.0, 0.0, 0.0};

    for (int d0 = 0; d0 < DD; d0 += 64) {
        #pragma unroll
        for (int it = 0; it < 8; ++it) {
            int l = tid + 256 * it;
            int r = l >> 6, c = l & 63;
            A[r][c]  = x[(size_t)(n0 + r) * DD + d0 + c];
            Bm[r][c] = x[(size_t)(m0 + r) * DD + d0 + c];
        }
        __syncthreads();
        for (int d = 0; d < 64; d += 4) {
            float4 b4 = *(const float4*)&Bm[tx][d];
            #pragma unroll
            for (int r = 0; r < 4; ++r) {
                float4 a4 = *(const float4*)&A[ty + 8 * r][d];
                dot[r] += (double)a4.x * (double)b4.x + (double)a4.y * (double)b4.y
                        + (double)a4.z * (double)b4.z + (double)a4.w * (double)b4.w;
            }
        }
        __syncthreads();
    }
    double in_m = invn_d[m0 + tx];
    #pragma unroll
    for (int r = 0; r < 4; ++r) {
        int n = n0 + ty + 8 * r, m = m0 + tx;
        double v = dot[r] * invn_d[n] * in_m;
        simd[(size_t)n * NN + m] = v;
        simd[(size_t)m * NN + n] = v;
    }
}

// -------------------------------------------------- top-k (K=16) + adjacency
__global__ __launch_bounds__(256) void k_topk(const double* __restrict__ simd,
                                              unsigned char* __restrict__ adj) {
    int n = blockIdx.x;
    __shared__ double row[NN];
    __shared__ double wmax[4];
    __shared__ int    widx[4];
    int tid = threadIdx.x;
    int wid = tid >> 6, lane = tid & 63;
    for (int m = tid; m < NN; m += 256)
        row[m] = (m == n) ? -INFINITY : simd[(size_t)n * NN + m];
    if (tid == 0) adj[(size_t)n * NN + n] = 1;
    __syncthreads();
    for (int itr = 0; itr < TOPK; ++itr) {
        double bv = -INFINITY; int bi = NN;
        for (int m = tid; m < NN; m += 256) {
            double v = row[m];
            if (v > bv) { bv = v; bi = m; }
        }
        for (int off = 32; off > 0; off >>= 1) {
            double ov = __shfl_down(bv, off);
            int    oi = __shfl_down(bi, off);
            if (ov > bv || (ov == bv && oi < bi)) { bv = ov; bi = oi; }
        }
        if (lane == 0) { wmax[wid] = bv; widx[wid] = bi; }
        __syncthreads();
        if (tid == 0) {
            double fv = wmax[0]; int fi = widx[0];
            #pragma unroll
            for (int w = 1; w < 4; ++w) {
                if (wmax[w] > fv || (wmax[w] == fv && widx[w] < fi)) {
                    fv = wmax[w]; fi = widx[w];
                }
            }
            row[fi] = -INFINITY;
            adj[(size_t)n * NN + fi] = 1;
            adj[(size_t)fi * NN + n] = 1;
        }
        __syncthreads();
    }
}

// ------------------------------------- compact neighbor lists (ordered scan)
__global__ __launch_bounds__(256) void k_nbr(const unsigned char* __restrict__ adj,
                                             unsigned short* __restrict__ nbr_idx,
                                             int* __restrict__ nbr_cnt) {
    int n = blockIdx.x;
    int tid = threadIdx.x;
    __shared__ int cnts[256];
    int local[3]; int c = 0;
    #pragma unroll
    for (int i = 0; i < 3; ++i) {
        int m = 3 * tid + i;
        if (adj[(size_t)n * NN + m]) local[c++] = m;
    }
    cnts[tid] = c;
    __syncthreads();
    for (int off = 1; off < 256; off <<= 1) {
        int v = (tid >= off) ? cnts[tid - off] : 0;
        __syncthreads();
        cnts[tid] += v;
        __syncthreads();
    }
    int start = cnts[tid] - c;
    for (int i = 0; i < c; ++i)
        nbr_idx[(size_t)n * NN + start + i] = (unsigned short)local[i];
    if (tid == 255) nbr_cnt[n] = cnts[255];
}

// ------------------------- sparse edge features + edge MLP (neighbors only)
__global__ __launch_bounds__(256) void k_edge_sp(const float* __restrict__ x,
                                                 const double* __restrict__ nrm2_d,
                                                 const double* __restrict__ simd,
                                                 const unsigned short* __restrict__ nbr_idx,
                                                 const int* __restrict__ nbr_cnt,
                                                 const float* __restrict__ e1_w,
                                                 const float* __restrict__ e1_b,
                                                 const float* __restrict__ e2_w,
                                                 const float* __restrict__ e2_b,
                                                 const float* __restrict__ gate_p,
                                                 float* __restrict__ bias_sp) {
    int n = blockIdx.x;
    int tid = threadIdx.x;
    int w = tid >> 6, l = tid & 63;
    int cnt = nbr_cnt[n];
    float xa[4];
    #pragma unroll
    for (int i = 0; i < 4; ++i) xa[i] = x[(size_t)n * DD + l + 64 * i];
    double nrm2n = nrm2_d[n];
    double nrmn  = sqrt(nrm2n);
    float gate = gate_p[0];

    for (int j = w; j < cnt; j += 4) {
        int m = nbr_idx[(size_t)n * NN + j];
        float sab = 0.f, mab = 0.f;
        #pragma unroll
        for (int i = 0; i < 4; ++i) {
            float xb = x[(size_t)m * DD + l + 64 * i];
            float ad = fabsf(xa[i] - xb);
            sab += ad;
            mab = fmaxf(mab, ad);
        }
        for (int off = 32; off > 0; off >>= 1) {
            sab += __shfl_xor(sab, off);
            mab = fmaxf(mab, __shfl_xor(mab, off));
        }
        if (l == 0) {
            double s_d   = simd[(size_t)n * NN + m];
            double nrm2m = nrm2_d[m];
            double dot   = s_d * nrmn * sqrt(nrm2m);
            double l2sq  = fmax(nrm2n + nrm2m - 2.0 * dot, 0.0);
            float ef0 = (float)s_d;
            float ef1 = (float)(sqrt(l2sq) * (1.0 / 16.0));
            float ef2 = sab * (1.f / 256.f);
            float ef3 = mab;
            float hbuf[8];
            #pragma unroll
            for (int jj = 0; jj < 8; ++jj) {
                float hv = e1_b[jj] + ef0 * e1_w[0 * 8 + jj] + ef1 * e1_w[1 * 8 + jj]
                         + ef2 * e1_w[2 * 8 + jj] + ef3 * e1_w[3 * 8 + jj];
                hbuf[jj] = fmaxf(hv, 0.f);
            }
            #pragma unroll
            for (int hh = 0; hh < NHEAD; ++hh) {
                float bb = e2_b[hh];
                #pragma unroll
                for (int jj = 0; jj < 8; ++jj) bb += hbuf[jj] * e2_w[jj * 4 + hh];
                bias_sp[((size_t)hh * NN + n) * NN + j] = gate * bb;
            }
        }
    }
}

// ------------------------------------- sparse attention: one block per row n
__global__ __launch_bounds__(256) void k_attn_sp(const float* __restrict__ q,
                                                 const float* __restrict__ k,
                                                 const float* __restrict__ v,
                                                 const float* __restrict__ bias_sp,
                                                 const unsigned short* __restrict__ nbr_idx,
                                                 const int* __restrict__ nbr_cnt,
                                                 float* __restrict__ ctx,
                                                 unsigned short* __restrict__ ctxb) {
    int n = blockIdx.x;
    int tid = threadIdx.x;
    int h = tid >> 6, l = tid & 63;
    __shared__ unsigned short idxs[NN];
    __shared__ float w_sh[NHEAD][NN];
    __shared__ float qsh[NHEAD][HDIM];
    int cnt = nbr_cnt[n];
    for (int j = tid; j < cnt; j += 256) idxs[j] = nbr_idx[(size_t)n * NN + j];
    qsh[h][l] = q[((size_t)h * NN + n) * HDIM + l];
    __syncthreads();

    float lmax = -INFINITY;
    for (int j = l; j < cnt; j += 64) {
        int m = idxs[j];
        const float4* kr = (const float4*)(k + ((size_t)h * NN + m) * HDIM);
        float dotv = 0.f;
        #pragma unroll
        for (int d4 = 0; d4 < HDIM / 4; ++d4) {
            float4 kv = kr[d4];
            dotv += qsh[h][4 * d4 + 0] * kv.x + qsh[h][4 * d4 + 1] * kv.y
                  + qsh[h][4 * d4 + 2] * kv.z + qsh[h][4 * d4 + 3] * kv.w;
        }
        w_sh[h][j] = dotv * 0.125f + bias_sp[((size_t)h * NN + n) * NN + j];
        lmax = fmaxf(lmax, w_sh[h][j]);
    }
    for (int off = 32; off > 0; off >>= 1)
        lmax = fmaxf(lmax, __shfl_xor(lmax, off));

    float lsum = 0.f;
    for (int j = l; j < cnt; j += 64) {
        float e = expf(w_sh[h][j] - lmax);
        w_sh[h][j] = e;
        lsum += e;
    }
    for (int off = 32; off > 0; off >>= 1) lsum += __shfl_xor(lsum, off);
    float inv = 1.f / lsum;
    __syncthreads();

    float acc = 0.f;
    for (int j = 0; j < cnt; ++j)
        acc += w_sh[h][j] * v[((size_t)h * NN + idxs[j]) * HDIM + l];
    float r = acc * inv;
    ctx [(size_t)n * DD + h * HDIM + l] = r;
    ctxb[(size_t)n * DD + h * HDIM + l] = f2bf(r);
}

// ---------------------- MFMA bf16 GEMM, 64x64 tile, 4 waves, gated on flag
// MODE 0: out fp32 = A@B+bias   MODE 1: += resid   MODE 2: qkv scatter
// MODE 3: outb bf16 = A@B+bias
template<int KD, int MODE, bool CONCAT>
__global__ __launch_bounds__(256) void k_gemm_mf(const float* __restrict__ flag,
                                                 const unsigned short* __restrict__ A,
                                                 const unsigned short* __restrict__ A2,
                                                 const float* __restrict__ B,
                                                 const float* __restrict__ bias,
                                                 const float* __restrict__ resid,
                                                 float* __restrict__ out,
                                                 unsigned short* __restrict__ outb,
                                                 float* __restrict__ q,
                                                 float* __restrict__ k,
                                                 float* __restrict__ v,
                                                 int ncols) {
    if (flag[0] == 0.f) return;
    __shared__ unsigned short As[64][40];
    __shared__ unsigned short Bs[64][40];
    int n0 = blockIdx.y * 64, c0 = blockIdx.x * 64;
    int tid = threadIdx.x;
    int wid = tid >> 6, lane = tid & 63;
    int wr = wid >> 1, wc = wid & 1;
    f32x4 zero = {0.f, 0.f, 0.f, 0.f};
    f32x4 acc[2][2];
    acc[0][0] = zero; acc[0][1] = zero; acc[1][0] = zero; acc[1][1] = zero;

    int s_arow = tid >> 2, s_ak = (tid & 3) * 8;
    int s_bk = tid >> 3,  s_bc = (tid & 7) * 8;
    int fr = lane & 15, fk = (lane >> 4) * 8, fg = lane >> 4;

    for (int k0 = 0; k0 < KD; k0 += 32) {
        const unsigned short* Asrc = A; int koff = k0;
        int lda = CONCAT ? 256 : KD;
        if (CONCAT && k0 >= 256) { Asrc = A2; koff = k0 - 256; }
        *(short8*)&As[s_arow][s_ak] =
            *(const short8*)&Asrc[(size_t)(n0 + s_arow) * lda + koff + s_ak];
        float4 b0 = *(const float4*)&B[(size_t)(k0 + s_bk) * ncols + c0 + s_bc];
        float4 b1 = *(const float4*)&B[(size_t)(k0 + s_bk) * ncols + c0 + s_bc + 4];
        Bs[s_bc + 0][s_bk] = f2bf(b0.x);
        Bs[s_bc + 1][s_bk] = f2bf(b0.y);
        Bs[s_bc + 2][s_bk] = f2bf(b0.z);
        Bs[s_bc + 3][s_bk] = f2bf(b0.w);
        Bs[s_bc + 4][s_bk] = f2bf(b1.x);
        Bs[s_bc + 5][s_bk] = f2bf(b1.y);
        Bs[s_bc + 6][s_bk] = f2bf(b1.z);
        Bs[s_bc + 7][s_bk] = f2bf(b1.w);
        __syncthreads();
        short8 af0 = *(const short8*)&As[wr * 32 + 0  + fr][fk];
        short8 af1 = *(const short8*)&As[wr * 32 + 16 + fr][fk];
        short8 bf0 = *(const short8*)&Bs[wc * 32 + 0  + fr][fk];
        short8 bf1 = *(const short8*)&Bs[wc * 32 + 16 + fr][fk];
        acc[0][0] = __builtin_amdgcn_mfma_f32_16x16x32_bf16(af0, bf0, acc[0][0], 0, 0, 0);
        acc[0][1] = __builtin_amdgcn_mfma_f32_16x16x32_bf16(af0, bf1, acc[0][1], 0, 0, 0);
        acc[1][0] = __builtin_amdgcn_mfma_f32_16x16x32_bf16(af1, bf0, acc[1][0], 0, 0, 0);
        acc[1][1] = __builtin_amdgcn_mfma_f32_16x16x32_bf16(af1, bf1, acc[1][1], 0, 0, 0);
        __syncthreads();
    }

    #pragma unroll
    for (int j = 0; j < 2; ++j) {
        int c = c0 + wc * 32 + j * 16 + fr;
        if (MODE == 2) {
            int hh = c / 192, rem = c % 192, hd = rem / 3, s = rem % 3;
            float* dst = (s == 0) ? q : (s == 1) ? k : v;
            float bb = bias[c];
            #pragma unroll
            for (int i = 0; i < 2; ++i)
                #pragma unroll
                for (int r = 0; r < 4; ++r) {
                    int n = n0 + wr * 32 + i * 16 + fg * 4 + r;
                    dst[((size_t)hh * NN + n) * HDIM + hd] = acc[i][j][r] + bb;
                }
        } else {
            float bb = bias[c];
            #pragma unroll
            for (int i = 0; i < 2; ++i)
                #pragma unroll
                for (int r = 0; r < 4; ++r) {
                    int n = n0 + wr * 32 + i * 16 + fg * 4 + r;
                    float val = acc[i][j][r] + bb;
                    if (MODE == 1) val += resid[(size_t)n * ncols + c];
                    if (MODE == 3) outb[(size_t)n * ncols + c] = f2bf(val);
                    else           out [(size_t)n * ncols + c] = val;
                }
        }
    }
}

// ----------------- fp32 fallback GEMM (gated: runs only if MFMA probe fails)
template<int KD, int MODE, bool CONCAT>
__global__ __launch_bounds__(256) void k_gemm64(const float* __restrict__ flag,
                                                const float* __restrict__ A,
                                                const float* __restrict__ A2,
                                                const float* __restrict__ B,
                                                const float* __restrict__ bias,
                                                const float* __restrict__ resid,
                                                float* __restrict__ out,
                                                float* __restrict__ q,
                                                float* __restrict__ k,
                                                float* __restrict__ v,
                                                int ncols) {
    if (flag[0] != 0.f) return;
    __shared__ float As[16][68];
    __shared__ float Bs[16][68];
    int n0 = blockIdx.y * 64, c0 = blockIdx.x * 64;
    int tid = threadIdx.x;
    int tx = tid & 15, ty = tid >> 4;
    float acc[4][4] = {};

    int arow = tid >> 2, kq = tid & 3;
    int bk = tid >> 4, bc4 = (tid & 15) * 4;

    for (int k0 = 0; k0 < KD; k0 += 16) {
        const float* Asrc = A; int koff = k0; int lda = KD;
        if (CONCAT) {
            if (k0 < 256) { Asrc = A;  koff = k0;       lda = 256; }
            else          { Asrc = A2; koff = k0 - 256; lda = 256; }
        }
        float4 av = *(const float4*)&Asrc[(size_t)(n0 + arow) * lda + koff + kq * 4];
        float4 bv = *(const float4*)&B[(size_t)(k0 + bk) * ncols + c0 + bc4];
        As[kq * 4 + 0][arow] = av.x;
        As[kq * 4 + 1][arow] = av.y;
        As[kq * 4 + 2][arow] = av.z;
        As[kq * 4 + 3][arow] = av.w;
        *(float4*)&Bs[bk][bc4] = bv;
        __syncthreads();
        #pragma unroll
        for (int kk = 0; kk < 16; ++kk) {
            float4 a4 = *(const float4*)&As[kk][ty * 4];
            float4 b4 = *(const float4*)&Bs[kk][tx * 4];
            float aa[4] = {a4.x, a4.y, a4.z, a4.w};
            float bb[4] = {b4.x, b4.y, b4.z, b4.w};
            #pragma unroll
            for (int i = 0; i < 4; ++i)
                #pragma unroll
                for (int jj = 0; jj < 4; ++jj)
                    acc[i][jj] += aa[i] * bb[jj];
        }
        __syncthreads();
    }

    if (MODE == 2) {
        #pragma unroll
        for (int jj = 0; jj < 4; ++jj) {
            int c = c0 + tx * 4 + jj;
            int hh = c / 192, rem = c % 192, hd = rem / 3, s = rem % 3;
            float* dst = (s == 0) ? q : (s == 1) ? k : v;
            float bb = bias[c];
            #pragma unroll
            for (int i = 0; i < 4; ++i) {
                int n = n0 + ty * 4 + i;
                dst[((size_t)hh * NN + n) * HDIM + hd] = acc[i][jj] + bb;
            }
        }
    } else {
        float4 b4 = *(const float4*)&bias[c0 + tx * 4];
        float bb[4] = {b4.x, b4.y, b4.z, b4.w};
        #pragma unroll
        for (int i = 0; i < 4; ++i) {
            int n = n0 + ty * 4 + i;
            float4 o;
            o.x = acc[i][0] + bb[0];
            o.y = acc[i][1] + bb[1];
            o.z = acc[i][2] + bb[2];
            o.w = acc[i][3] + bb[3];
            if (MODE == 1) {
                float4 r4 = *(const float4*)&resid[(size_t)n * ncols + c0 + tx * 4];
                o.x += r4.x; o.y += r4.y; o.z += r4.z; o.w += r4.w;
            }
            *(float4*)&out[(size_t)n * ncols + c0 + tx * 4] = o;
        }
    }
}

// ------------------------------- LayerNorm + exact GELU (+ bf16 copy of y)
__global__ __launch_bounds__(256) void k_ln_gelu(float* __restrict__ y,
                                                 const float* __restrict__ g,
                                                 const float* __restrict__ b,
                                                 unsigned short* __restrict__ ybb) {
    int n = blockIdx.x;
    int tid = threadIdx.x;
    float* row = y + (size_t)n * 512;
    __shared__ float red[256];
    float v0 = row[tid], v1 = row[tid + 256];

    red[tid] = v0 + v1; __syncthreads();
    for (int s = 128; s > 0; s >>= 1) {
        if (tid < s) red[tid] += red[tid + s];
        __syncthreads();
    }
    float mu = red[0] * (1.f / 512.f);
    __syncthreads();

    float d0 = v0 - mu, d1 = v1 - mu;
    red[tid] = d0 * d0 + d1 * d1; __syncthreads();
    for (int s = 128; s > 0; s >>= 1) {
        if (tid < s) red[tid] += red[tid + s];
        __syncthreads();
    }
    float var = red[0] * (1.f / 512.f);
    float rstd = 1.f / sqrtf(var + 1e-5f);

    float z0 = d0 * rstd * g[tid] + b[tid];
    float z1 = d1 * rstd * g[tid + 256] + b[tid + 256];
    float o0 = 0.5f * z0 * (1.f + erff(z0 * 0.70710678118654752f));
    float o1 = 0.5f * z1 * (1.f + erff(z1 * 0.70710678118654752f));
    row[tid]       = o0;
    row[tid + 256] = o1;
    ybb[(size_t)n * 512 + tid]       = f2bf(o0);
    ybb[(size_t)n * 512 + tid + 256] = f2bf(o1);
}

// --------------------------------------------------------------------- host
extern "C" void kernel_launch(void* const* d_in, const int* in_sizes, int n_in,
                              void* d_out, int out_size, void* d_ws, size_t ws_size,
                              hipStream_t stream) {
    const float* x       = (const float*)d_in[0];
    const float* Wqkv_w  = (const float*)d_in[1];
    const float* Wqkv_b  = (const float*)d_in[2];
    const float* out_w   = (const float*)d_in[3];
    const float* out_b   = (const float*)d_in[4];
    const float* ffn1_w  = (const float*)d_in[5];
    const float* ffn1_b  = (const float*)d_in[6];
    const float* ln_g    = (const float*)d_in[7];
    const float* ln_b    = (const float*)d_in[8];
    const float* ffn2_w  = (const float*)d_in[9];
    const float* ffn2_b  = (const float*)d_in[10];
    const float* e1_w    = (const float*)d_in[11];
    const float* e1_b    = (const float*)d_in[12];
    const float* e2_w    = (const float*)d_in[13];
    const float* e2_b    = (const float*)d_in[14];
    const float* gate    = (const float*)d_in[15];

    char* base = (char*)d_ws;
    double* simd   = (double*)base;            base += (size_t)NN * NN * 8;
    double* nrm2_d = (double*)base;            base += NN * 8;
    double* invn_d = (double*)base;            base += NN * 8;
    float* bias_sp = (float*)base;             base += (size_t)NHEAD * NN * NN * 4;
    float* qb      = (float*)base;             base += (size_t)NN * DD * 4;
    float* kb      = (float*)base;             base += (size_t)NN * DD * 4;
    float* vb      = (float*)base;             base += (size_t)NN * DD * 4;
    float* ctx     = (float*)base;             base += (size_t)NN * DD * 4;
    float* msg     = (float*)base;             base += (size_t)NN * DD * 4;
    float* yb      = (float*)base;             base += (size_t)NN * 512 * 4;
    int* nbr_cnt   = (int*)base;               base += NN * 4;
    unsigned short* nbr_idx = (unsigned short*)base; base += (size_t)NN * NN * 2;
    unsigned char* adj = (unsigned char*)base;  base += (size_t)NN * NN;
    unsigned short* xbf  = (unsigned short*)base; base += (size_t)NN * DD * 2;
    unsigned short* msgb = (unsigned short*)base; base += (size_t)NN * DD * 2;
    unsigned short* ctxb = (unsigned short*)base; base += (size_t)NN * DD * 2;
    unsigned short* ybb  = (unsigned short*)base; base += (size_t)NN * 512 * 2;
    float* flag    = (float*)base;             base += 16;

    hipMemsetAsync(adj, 0, (size_t)NN * NN, stream);

    k_probe<<<1, 64, 0, stream>>>(flag);

    k_norms<<<NN, 64, 0, stream>>>(x, nrm2_d, invn_d, xbf);

    k_sim<<<dim3(NN / 32, NN / 32), 256, 0, stream>>>(x, invn_d, simd);

    k_topk<<<NN, 256, 0, stream>>>(simd, adj);

    k_nbr<<<NN, 256, 0, stream>>>(adj, nbr_idx, nbr_cnt);

    k_edge_sp<<<NN, 256, 0, stream>>>(x, nrm2_d, simd, nbr_idx, nbr_cnt,
                                      e1_w, e1_b, e2_w, e2_b, gate, bias_sp);

    // QKV
    k_gemm_mf<DD, 2, false><<<dim3(12, 12), 256, 0, stream>>>(
        flag, xbf, nullptr, Wqkv_w, Wqkv_b, nullptr, nullptr, nullptr, qb, kb, vb, 3 * DD);
    k_gemm64<DD, 2, false><<<dim3(12, 12), 256, 0, stream>>>(
        flag, x, nullptr, Wqkv_w, Wqkv_b, nullptr, nullptr, qb, kb, vb, 3 * DD);

    k_attn_sp<<<NN, 256, 0, stream>>>(qb, kb, vb, bias_sp, nbr_idx, nbr_cnt, ctx, ctxb);

    // msg = ctx @ out_w + out_b   (mfma path -> msgb bf16, fb path -> msg fp32)
    k_gemm_mf<DD, 3, false><<<dim3(4, 12), 256, 0, stream>>>(
        flag, ctxb, nullptr, out_w, out_b, nullptr, nullptr, msgb, nullptr, nullptr, nullptr, DD);
    k_gemm64<DD, 0, false><<<dim3(4, 12), 256, 0, stream>>>(
        flag, ctx, nullptr, out_w, out_b, nullptr, msg, nullptr, nullptr, nullptr, DD);

    // y = [x, msg] @ ffn1_w + ffn1_b
    k_gemm_mf<512, 0, true><<<dim3(8, 12), 256, 0, stream>>>(
        flag, xbf, msgb, ffn1_w, ffn1_b, nullptr, yb, nullptr, nullptr, nullptr, nullptr, 512);
    k_gemm64<512, 0, true><<<dim3(8, 12), 256, 0, stream>>>(
        flag, x, msg, ffn1_w, ffn1_b, nullptr, yb, nullptr, nullptr, nullptr, 512);

    k_ln_gelu<<<NN, 256, 0, stream>>>(yb, ln_g, ln_b, ybb);

    // out = x + y @ ffn2_w + ffn2_b
    k_gemm_mf<512, 1, false><<<dim3(4, 12), 256, 0, stream>>>(
        flag, ybb, nullptr, ffn2_w, ffn2_b, x, (float*)d_out, nullptr, nullptr, nullptr, nullptr, DD);
    k_gemm64<512, 1, false><<<dim3(4, 12), 256, 0, stream>>>(
        flag, yb, nullptr, ffn2_w, ffn2_b, x, (float*)d_out, nullptr, nullptr, nullptr, DD);
}

// Round 5
// 134.501 us; speedup vs baseline: 1.7412x; 1.0647x over previous
//
#include <hip/hip_runtime.h>
#include <hip/hip_bf16.h>
#include <math.h>

#define NN 768
#define DD 256
#define NHEAD 4
#define HDIM 64
#define TOPK 16

typedef __attribute__((ext_vector_type(8))) short short8;
typedef __attribute__((ext_vector_type(4))) float f32x4;

__device__ __forceinline__ unsigned short f2bf(float f) {
    unsigned u = __float_as_uint(f);
    unsigned r = u + 0x7fffu + ((u >> 16) & 1u);
    return (unsigned short)(r >> 16);
}

// ------------------------------- row norms (fp64 for topk) + x -> bf16 copy
__global__ __launch_bounds__(64) void k_norms(const float* __restrict__ x,
                                              double* __restrict__ nrm2_d,
                                              double* __restrict__ invn_d,
                                              unsigned short* __restrict__ xb) {
    int n = blockIdx.x;
    int lane = threadIdx.x;
    const float* row = x + (size_t)n * DD;
    double s = 0.0;
    #pragma unroll
    for (int i = 0; i < 4; ++i) {
        float v = row[lane + 64 * i];
        xb[(size_t)n * DD + lane + 64 * i] = f2bf(v);
        s += (double)v * (double)v;
    }
    for (int off = 32; off > 0; off >>= 1) s += __shfl_down(s, off);
    if (lane == 0) {
        nrm2_d[n] = s;
        invn_d[n] = 1.0 / fmax(sqrt(s), 1e-12);
    }
}

// ------------------- dense fp64 similarity, triangular grid (m0 >= n0 only)
__global__ __launch_bounds__(256) void k_sim(const float* __restrict__ x,
                                             const double* __restrict__ invn_d,
                                             double* __restrict__ simd) {
    // decode linear block id -> (r, c) with c <= r over 24x24 tiles
    int b = blockIdx.x;
    int r = (int)((sqrtf(8.f * (float)b + 1.f) - 1.f) * 0.5f);
    while ((r + 1) * (r + 2) / 2 <= b) ++r;
    while (r * (r + 1) / 2 > b) --r;
    int c = b - r * (r + 1) / 2;
    int n0 = c * 32, m0 = r * 32;   // m0 >= n0

    __shared__ float A[32][68];
    __shared__ float Bm[32][68];
    int tid = threadIdx.x;
    int tx = tid & 31, ty = tid >> 5;
    double dot[4] = {0.0, 0.0, 0.0, 0.0};

    for (int d0 = 0; d0 < DD; d0 += 64) {
        #pragma unroll
        for (int it = 0; it < 8; ++it) {
            int l = tid + 256 * it;
            int rr = l >> 6, cc = l & 63;
            A[rr][cc]  = x[(size_t)(n0 + rr) * DD + d0 + cc];
            Bm[rr][cc] = x[(size_t)(m0 + rr) * DD + d0 + cc];
        }
        __syncthreads();
        for (int d = 0; d < 64; d += 4) {
            float4 b4 = *(const float4*)&Bm[tx][d];
            #pragma unroll
            for (int rr = 0; rr < 4; ++rr) {
                float4 a4 = *(const float4*)&A[ty + 8 * rr][d];
                dot[rr] += (double)a4.x * (double)b4.x + (double)a4.y * (double)b4.y
                         + (double)a4.z * (double)b4.z + (double)a4.w * (double)b4.w;
            }
        }
        __syncthreads();
    }
    double in_m = invn_d[m0 + tx];
    #pragma unroll
    for (int rr = 0; rr < 4; ++rr) {
        int n = n0 + ty + 8 * rr, m = m0 + tx;
        double v = dot[rr] * invn_d[n] * in_m;
        simd[(size_t)n * NN + m] = v;
        simd[(size_t)m * NN + n] = v;
    }
}

// -------------------------------------------------- top-k (K=16) + adjacency
__global__ __launch_bounds__(256) void k_topk(const double* __restrict__ simd,
                                              unsigned char* __restrict__ adj) {
    int n = blockIdx.x;
    __shared__ double row[NN];
    __shared__ double wmax[4];
    __shared__ int    widx[4];
    int tid = threadIdx.x;
    int wid = tid >> 6, lane = tid & 63;
    for (int m = tid; m < NN; m += 256)
        row[m] = (m == n) ? -INFINITY : simd[(size_t)n * NN + m];
    if (tid == 0) adj[(size_t)n * NN + n] = 1;
    __syncthreads();
    for (int itr = 0; itr < TOPK; ++itr) {
        double bv = -INFINITY; int bi = NN;
        for (int m = tid; m < NN; m += 256) {
            double v = row[m];
            if (v > bv) { bv = v; bi = m; }
        }
        for (int off = 32; off > 0; off >>= 1) {
            double ov = __shfl_down(bv, off);
            int    oi = __shfl_down(bi, off);
            if (ov > bv || (ov == bv && oi < bi)) { bv = ov; bi = oi; }
        }
        if (lane == 0) { wmax[wid] = bv; widx[wid] = bi; }
        __syncthreads();
        if (tid == 0) {
            double fv = wmax[0]; int fi = widx[0];
            #pragma unroll
            for (int w = 1; w < 4; ++w) {
                if (wmax[w] > fv || (wmax[w] == fv && widx[w] < fi)) {
                    fv = wmax[w]; fi = widx[w];
                }
            }
            row[fi] = -INFINITY;
            adj[(size_t)n * NN + fi] = 1;
            adj[(size_t)fi * NN + n] = 1;
        }
        __syncthreads();
    }
}

// ------------------------------------- compact neighbor lists (ordered scan)
__global__ __launch_bounds__(256) void k_nbr(const unsigned char* __restrict__ adj,
                                             unsigned short* __restrict__ nbr_idx,
                                             int* __restrict__ nbr_cnt) {
    int n = blockIdx.x;
    int tid = threadIdx.x;
    __shared__ int cnts[256];
    int local[3]; int c = 0;
    #pragma unroll
    for (int i = 0; i < 3; ++i) {
        int m = 3 * tid + i;
        if (adj[(size_t)n * NN + m]) local[c++] = m;
    }
    cnts[tid] = c;
    __syncthreads();
    for (int off = 1; off < 256; off <<= 1) {
        int v = (tid >= off) ? cnts[tid - off] : 0;
        __syncthreads();
        cnts[tid] += v;
        __syncthreads();
    }
    int start = cnts[tid] - c;
    for (int i = 0; i < c; ++i)
        nbr_idx[(size_t)n * NN + start + i] = (unsigned short)local[i];
    if (tid == 255) nbr_cnt[n] = cnts[255];
}

// ---- fused: edge features + edge MLP + sparse attention + msg GEMV (per row)
__global__ __launch_bounds__(256) void k_edge_attn(
        const float* __restrict__ x,
        const double* __restrict__ nrm2_d,
        const double* __restrict__ simd,
        const unsigned short* __restrict__ nbr_idx,
        const int* __restrict__ nbr_cnt,
        const float* __restrict__ e1_w, const float* __restrict__ e1_b,
        const float* __restrict__ e2_w, const float* __restrict__ e2_b,
        const float* __restrict__ gate_p,
        const float* __restrict__ q, const float* __restrict__ k,
        const float* __restrict__ v,
        const float* __restrict__ out_w, const float* __restrict__ out_b,
        unsigned short* __restrict__ msgb) {
    int n = blockIdx.x;
    int tid = threadIdx.x;
    int w = tid >> 6, l = tid & 63;
    __shared__ unsigned short idxs[NN];
    __shared__ float w_sh[NHEAD][NN];
    __shared__ float qsh[NHEAD][HDIM];
    __shared__ float ctx_sh[DD];
    int cnt = nbr_cnt[n];
    for (int j = tid; j < cnt; j += 256) idxs[j] = nbr_idx[(size_t)n * NN + j];
    qsh[w][l] = q[((size_t)w * NN + n) * HDIM + l];
    __syncthreads();

    // ---- Phase A: edge features + MLP -> w_sh[h][j] = gate*bias
    float xa[4];
    #pragma unroll
    for (int i = 0; i < 4; ++i) xa[i] = x[(size_t)n * DD + l + 64 * i];
    double nrm2n = nrm2_d[n];
    double nrmn  = sqrt(nrm2n);
    float gate = gate_p[0];

    for (int j = w; j < cnt; j += 4) {
        int m = idxs[j];
        float sab = 0.f, mab = 0.f;
        #pragma unroll
        for (int i = 0; i < 4; ++i) {
            float xb = x[(size_t)m * DD + l + 64 * i];
            float ad = fabsf(xa[i] - xb);
            sab += ad;
            mab = fmaxf(mab, ad);
        }
        for (int off = 32; off > 0; off >>= 1) {
            sab += __shfl_xor(sab, off);
            mab = fmaxf(mab, __shfl_xor(mab, off));
        }
        if (l == 0) {
            double s_d   = simd[(size_t)n * NN + m];
            double nrm2m = nrm2_d[m];
            double dotd  = s_d * nrmn * sqrt(nrm2m);
            double l2sq  = fmax(nrm2n + nrm2m - 2.0 * dotd, 0.0);
            float ef0 = (float)s_d;
            float ef1 = (float)(sqrt(l2sq) * (1.0 / 16.0));
            float ef2 = sab * (1.f / 256.f);
            float ef3 = mab;
            float hbuf[8];
            #pragma unroll
            for (int jj = 0; jj < 8; ++jj) {
                float hv = e1_b[jj] + ef0 * e1_w[0 * 8 + jj] + ef1 * e1_w[1 * 8 + jj]
                         + ef2 * e1_w[2 * 8 + jj] + ef3 * e1_w[3 * 8 + jj];
                hbuf[jj] = fmaxf(hv, 0.f);
            }
            #pragma unroll
            for (int hh = 0; hh < NHEAD; ++hh) {
                float bb = e2_b[hh];
                #pragma unroll
                for (int jj = 0; jj < 8; ++jj) bb += hbuf[jj] * e2_w[jj * 4 + hh];
                w_sh[hh][j] = gate * bb;
            }
        }
    }
    __syncthreads();

    // ---- Phase B: logits + softmax + PV (h = w, lane = l)
    int h = w;
    float lmax = -INFINITY;
    for (int j = l; j < cnt; j += 64) {
        int m = idxs[j];
        const float4* kr = (const float4*)(k + ((size_t)h * NN + m) * HDIM);
        float dotv = 0.f;
        #pragma unroll
        for (int d4 = 0; d4 < HDIM / 4; ++d4) {
            float4 kv = kr[d4];
            dotv += qsh[h][4 * d4 + 0] * kv.x + qsh[h][4 * d4 + 1] * kv.y
                  + qsh[h][4 * d4 + 2] * kv.z + qsh[h][4 * d4 + 3] * kv.w;
        }
        w_sh[h][j] = dotv * 0.125f + w_sh[h][j];
        lmax = fmaxf(lmax, w_sh[h][j]);
    }
    for (int off = 32; off > 0; off >>= 1)
        lmax = fmaxf(lmax, __shfl_xor(lmax, off));

    float lsum = 0.f;
    for (int j = l; j < cnt; j += 64) {
        float e = expf(w_sh[h][j] - lmax);
        w_sh[h][j] = e;
        lsum += e;
    }
    for (int off = 32; off > 0; off >>= 1) lsum += __shfl_xor(lsum, off);
    float inv = 1.f / lsum;
    __syncthreads();   // all w_sh writes visible

    float acc = 0.f;
    for (int j = 0; j < cnt; ++j)
        acc += w_sh[h][j] * v[((size_t)h * NN + idxs[j]) * HDIM + l];
    ctx_sh[h * HDIM + l] = acc * inv;
    __syncthreads();

    // ---- Phase C: msg = ctx @ out_w + out_b (fp32 GEMV), write bf16
    float mv = out_b[tid];
    #pragma unroll 4
    for (int kk = 0; kk < DD; ++kk)
        mv += ctx_sh[kk] * out_w[(size_t)kk * DD + tid];
    msgb[(size_t)n * DD + tid] = f2bf(mv);
}

// ---------------------- MFMA bf16 GEMM, 64x64 tile, 4 waves
// MODE 0: out fp32 = A@B+bias   MODE 1: += resid   MODE 2: qkv scatter
template<int KD, int MODE, bool CONCAT>
__global__ __launch_bounds__(256) void k_gemm_mf(const unsigned short* __restrict__ A,
                                                 const unsigned short* __restrict__ A2,
                                                 const float* __restrict__ B,
                                                 const float* __restrict__ bias,
                                                 const float* __restrict__ resid,
                                                 float* __restrict__ out,
                                                 float* __restrict__ q,
                                                 float* __restrict__ k,
                                                 float* __restrict__ v,
                                                 int ncols) {
    __shared__ unsigned short As[64][40];
    __shared__ unsigned short Bs[64][40];
    int n0 = blockIdx.y * 64, c0 = blockIdx.x * 64;
    int tid = threadIdx.x;
    int wid = tid >> 6, lane = tid & 63;
    int wr = wid >> 1, wc = wid & 1;
    f32x4 zero = {0.f, 0.f, 0.f, 0.f};
    f32x4 acc[2][2];
    acc[0][0] = zero; acc[0][1] = zero; acc[1][0] = zero; acc[1][1] = zero;

    int s_arow = tid >> 2, s_ak = (tid & 3) * 8;
    int s_bk = tid >> 3,  s_bc = (tid & 7) * 8;
    int fr = lane & 15, fk = (lane >> 4) * 8, fg = lane >> 4;

    for (int k0 = 0; k0 < KD; k0 += 32) {
        const unsigned short* Asrc = A; int koff = k0;
        int lda = CONCAT ? 256 : KD;
        if (CONCAT && k0 >= 256) { Asrc = A2; koff = k0 - 256; }
        *(short8*)&As[s_arow][s_ak] =
            *(const short8*)&Asrc[(size_t)(n0 + s_arow) * lda + koff + s_ak];
        float4 b0 = *(const float4*)&B[(size_t)(k0 + s_bk) * ncols + c0 + s_bc];
        float4 b1 = *(const float4*)&B[(size_t)(k0 + s_bk) * ncols + c0 + s_bc + 4];
        Bs[s_bc + 0][s_bk] = f2bf(b0.x);
        Bs[s_bc + 1][s_bk] = f2bf(b0.y);
        Bs[s_bc + 2][s_bk] = f2bf(b0.z);
        Bs[s_bc + 3][s_bk] = f2bf(b0.w);
        Bs[s_bc + 4][s_bk] = f2bf(b1.x);
        Bs[s_bc + 5][s_bk] = f2bf(b1.y);
        Bs[s_bc + 6][s_bk] = f2bf(b1.z);
        Bs[s_bc + 7][s_bk] = f2bf(b1.w);
        __syncthreads();
        short8 af0 = *(const short8*)&As[wr * 32 + 0  + fr][fk];
        short8 af1 = *(const short8*)&As[wr * 32 + 16 + fr][fk];
        short8 bf0 = *(const short8*)&Bs[wc * 32 + 0  + fr][fk];
        short8 bf1 = *(const short8*)&Bs[wc * 32 + 16 + fr][fk];
        acc[0][0] = __builtin_amdgcn_mfma_f32_16x16x32_bf16(af0, bf0, acc[0][0], 0, 0, 0);
        acc[0][1] = __builtin_amdgcn_mfma_f32_16x16x32_bf16(af0, bf1, acc[0][1], 0, 0, 0);
        acc[1][0] = __builtin_amdgcn_mfma_f32_16x16x32_bf16(af1, bf0, acc[1][0], 0, 0, 0);
        acc[1][1] = __builtin_amdgcn_mfma_f32_16x16x32_bf16(af1, bf1, acc[1][1], 0, 0, 0);
        __syncthreads();
    }

    #pragma unroll
    for (int j = 0; j < 2; ++j) {
        int c = c0 + wc * 32 + j * 16 + fr;
        if (MODE == 2) {
            int hh = c / 192, rem = c % 192, hd = rem / 3, s = rem % 3;
            float* dst = (s == 0) ? q : (s == 1) ? k : v;
            float bb = bias[c];
            #pragma unroll
            for (int i = 0; i < 2; ++i)
                #pragma unroll
                for (int r = 0; r < 4; ++r) {
                    int n = n0 + wr * 32 + i * 16 + fg * 4 + r;
                    dst[((size_t)hh * NN + n) * HDIM + hd] = acc[i][j][r] + bb;
                }
        } else {
            float bb = bias[c];
            #pragma unroll
            for (int i = 0; i < 2; ++i)
                #pragma unroll
                for (int r = 0; r < 4; ++r) {
                    int n = n0 + wr * 32 + i * 16 + fg * 4 + r;
                    float val = acc[i][j][r] + bb;
                    if (MODE == 1) val += resid[(size_t)n * ncols + c];
                    out[(size_t)n * ncols + c] = val;
                }
        }
    }
}

// ------------------------------- LayerNorm + exact GELU -> bf16
__global__ __launch_bounds__(256) void k_ln_gelu(const float* __restrict__ y,
                                                 const float* __restrict__ g,
                                                 const float* __restrict__ b,
                                                 unsigned short* __restrict__ ybb) {
    int n = blockIdx.x;
    int tid = threadIdx.x;
    const float* row = y + (size_t)n * 512;
    __shared__ float red[256];
    float v0 = row[tid], v1 = row[tid + 256];

    red[tid] = v0 + v1; __syncthreads();
    for (int s = 128; s > 0; s >>= 1) {
        if (tid < s) red[tid] += red[tid + s];
        __syncthreads();
    }
    float mu = red[0] * (1.f / 512.f);
    __syncthreads();

    float d0 = v0 - mu, d1 = v1 - mu;
    red[tid] = d0 * d0 + d1 * d1; __syncthreads();
    for (int s = 128; s > 0; s >>= 1) {
        if (tid < s) red[tid] += red[tid + s];
        __syncthreads();
    }
    float var = red[0] * (1.f / 512.f);
    float rstd = 1.f / sqrtf(var + 1e-5f);

    float z0 = d0 * rstd * g[tid] + b[tid];
    float z1 = d1 * rstd * g[tid + 256] + b[tid + 256];
    float o0 = 0.5f * z0 * (1.f + erff(z0 * 0.70710678118654752f));
    float o1 = 0.5f * z1 * (1.f + erff(z1 * 0.70710678118654752f));
    ybb[(size_t)n * 512 + tid]       = f2bf(o0);
    ybb[(size_t)n * 512 + tid + 256] = f2bf(o1);
}

// --------------------------------------------------------------------- host
extern "C" void kernel_launch(void* const* d_in, const int* in_sizes, int n_in,
                              void* d_out, int out_size, void* d_ws, size_t ws_size,
                              hipStream_t stream) {
    const float* x       = (const float*)d_in[0];
    const float* Wqkv_w  = (const float*)d_in[1];
    const float* Wqkv_b  = (const float*)d_in[2];
    const float* out_w   = (const float*)d_in[3];
    const float* out_b   = (const float*)d_in[4];
    const float* ffn1_w  = (const float*)d_in[5];
    const float* ffn1_b  = (const float*)d_in[6];
    const float* ln_g    = (const float*)d_in[7];
    const float* ln_b    = (const float*)d_in[8];
    const float* ffn2_w  = (const float*)d_in[9];
    const float* ffn2_b  = (const float*)d_in[10];
    const float* e1_w    = (const float*)d_in[11];
    const float* e1_b    = (const float*)d_in[12];
    const float* e2_w    = (const float*)d_in[13];
    const float* e2_b    = (const float*)d_in[14];
    const float* gate    = (const float*)d_in[15];

    char* base = (char*)d_ws;
    double* simd   = (double*)base;            base += (size_t)NN * NN * 8;
    double* nrm2_d = (double*)base;            base += NN * 8;
    double* invn_d = (double*)base;            base += NN * 8;
    float* qb      = (float*)base;             base += (size_t)NN * DD * 4;
    float* kb      = (float*)base;             base += (size_t)NN * DD * 4;
    float* vb      = (float*)base;             base += (size_t)NN * DD * 4;
    float* yb      = (float*)base;             base += (size_t)NN * 512 * 4;
    int* nbr_cnt   = (int*)base;               base += NN * 4;
    unsigned short* nbr_idx = (unsigned short*)base; base += (size_t)NN * NN * 2;
    unsigned char* adj = (unsigned char*)base;  base += (size_t)NN * NN;
    unsigned short* xbf  = (unsigned short*)base; base += (size_t)NN * DD * 2;
    unsigned short* msgb = (unsigned short*)base; base += (size_t)NN * DD * 2;
    unsigned short* ybb  = (unsigned short*)base; base += (size_t)NN * 512 * 2;

    hipMemsetAsync(adj, 0, (size_t)NN * NN, stream);

    k_norms<<<NN, 64, 0, stream>>>(x, nrm2_d, invn_d, xbf);

    k_sim<<<24 * 25 / 2, 256, 0, stream>>>(x, invn_d, simd);

    k_gemm_mf<DD, 2, false><<<dim3(12, 12), 256, 0, stream>>>(
        xbf, nullptr, Wqkv_w, Wqkv_b, nullptr, nullptr, qb, kb, vb, 3 * DD);

    k_topk<<<NN, 256, 0, stream>>>(simd, adj);

    k_nbr<<<NN, 256, 0, stream>>>(adj, nbr_idx, nbr_cnt);

    k_edge_attn<<<NN, 256, 0, stream>>>(x, nrm2_d, simd, nbr_idx, nbr_cnt,
                                        e1_w, e1_b, e2_w, e2_b, gate,
                                        qb, kb, vb, out_w, out_b, msgb);

    // y = [x, msg] @ ffn1_w + ffn1_b
    k_gemm_mf<512, 0, true><<<dim3(8, 12), 256, 0, stream>>>(
        xbf, msgb, ffn1_w, ffn1_b, nullptr, yb, nullptr, nullptr, nullptr, 512);

    k_ln_gelu<<<NN, 256, 0, stream>>>(yb, ln_g, ln_b, ybb);

    // out = x + y @ ffn2_w + ffn2_b
    k_gemm_mf<512, 1, false><<<dim3(4, 12), 256, 0, stream>>>(
        ybb, nullptr, ffn2_w, ffn2_b, x, (float*)d_out, nullptr, nullptr, nullptr, DD);
}

// Round 6
// 126.177 us; speedup vs baseline: 1.8560x; 1.0660x over previous
//
#include <hip/hip_runtime.h>
#include <hip/hip_bf16.h>
#include <math.h>

#define NN 768
#define DD 256
#define NHEAD 4
#define HDIM 64
#define TOPK 16

typedef __attribute__((ext_vector_type(8))) short short8;
typedef __attribute__((ext_vector_type(4))) float f32x4;

__device__ __forceinline__ unsigned short f2bf(float f) {
    unsigned u = __float_as_uint(f);
    unsigned r = u + 0x7fffu + ((u >> 16) & 1u);
    return (unsigned short)(r >> 16);
}

// ---------------- row norms (fp64 for topk) + sqrt + x -> bf16 copy
__global__ __launch_bounds__(64) void k_norms(const float* __restrict__ x,
                                              double* __restrict__ nrm2_d,
                                              double* __restrict__ nrm_d,
                                              double* __restrict__ invn_d,
                                              unsigned short* __restrict__ xb) {
    int n = blockIdx.x;
    int lane = threadIdx.x;
    const float* row = x + (size_t)n * DD;
    double s = 0.0;
    #pragma unroll
    for (int i = 0; i < 4; ++i) {
        float v = row[lane + 64 * i];
        xb[(size_t)n * DD + lane + 64 * i] = f2bf(v);
        s += (double)v * (double)v;
    }
    for (int off = 32; off > 0; off >>= 1) s += __shfl_down(s, off);
    if (lane == 0) {
        nrm2_d[n] = s;
        double nv = sqrt(s);
        nrm_d[n] = nv;
        invn_d[n] = 1.0 / fmax(nv, 1e-12);
    }
}

// ------------------- dense fp64 similarity, triangular grid (m0 >= n0 only)
__global__ __launch_bounds__(256) void k_sim(const float* __restrict__ x,
                                             const double* __restrict__ invn_d,
                                             double* __restrict__ simd) {
    int b = blockIdx.x;
    int r = (int)((sqrtf(8.f * (float)b + 1.f) - 1.f) * 0.5f);
    while ((r + 1) * (r + 2) / 2 <= b) ++r;
    while (r * (r + 1) / 2 > b) --r;
    int c = b - r * (r + 1) / 2;
    int n0 = c * 32, m0 = r * 32;   // m0 >= n0

    __shared__ float A[32][68];
    __shared__ float Bm[32][68];
    int tid = threadIdx.x;
    int tx = tid & 31, ty = tid >> 5;
    double dot[4] = {0.0, 0.0, 0.0, 0.0};

    for (int d0 = 0; d0 < DD; d0 += 64) {
        #pragma unroll
        for (int it = 0; it < 8; ++it) {
            int l = tid + 256 * it;
            int rr = l >> 6, cc = l & 63;
            A[rr][cc]  = x[(size_t)(n0 + rr) * DD + d0 + cc];
            Bm[rr][cc] = x[(size_t)(m0 + rr) * DD + d0 + cc];
        }
        __syncthreads();
        for (int d = 0; d < 64; d += 4) {
            float4 b4 = *(const float4*)&Bm[tx][d];
            #pragma unroll
            for (int rr = 0; rr < 4; ++rr) {
                float4 a4 = *(const float4*)&A[ty + 8 * rr][d];
                dot[rr] += (double)a4.x * (double)b4.x + (double)a4.y * (double)b4.y
                         + (double)a4.z * (double)b4.z + (double)a4.w * (double)b4.w;
            }
        }
        __syncthreads();
    }
    double in_m = invn_d[m0 + tx];
    #pragma unroll
    for (int rr = 0; rr < 4; ++rr) {
        int n = n0 + ty + 8 * rr, m = m0 + tx;
        double v = dot[rr] * invn_d[n] * in_m;
        simd[(size_t)n * NN + m] = v;
        simd[(size_t)m * NN + n] = v;
    }
}

// -------------------------------------------------- top-k (K=16) + adjacency
__global__ __launch_bounds__(256) void k_topk(const double* __restrict__ simd,
                                              unsigned char* __restrict__ adj) {
    int n = blockIdx.x;
    __shared__ double row[NN];
    __shared__ double wmax[4];
    __shared__ int    widx[4];
    int tid = threadIdx.x;
    int wid = tid >> 6, lane = tid & 63;
    for (int m = tid; m < NN; m += 256)
        row[m] = (m == n) ? -INFINITY : simd[(size_t)n * NN + m];
    if (tid == 0) adj[(size_t)n * NN + n] = 1;
    __syncthreads();
    for (int itr = 0; itr < TOPK; ++itr) {
        double bv = -INFINITY; int bi = NN;
        for (int m = tid; m < NN; m += 256) {
            double v = row[m];
            if (v > bv) { bv = v; bi = m; }
        }
        for (int off = 32; off > 0; off >>= 1) {
            double ov = __shfl_down(bv, off);
            int    oi = __shfl_down(bi, off);
            if (ov > bv || (ov == bv && oi < bi)) { bv = ov; bi = oi; }
        }
        if (lane == 0) { wmax[wid] = bv; widx[wid] = bi; }
        __syncthreads();
        if (tid == 0) {
            double fv = wmax[0]; int fi = widx[0];
            #pragma unroll
            for (int w = 1; w < 4; ++w) {
                if (wmax[w] > fv || (wmax[w] == fv && widx[w] < fi)) {
                    fv = wmax[w]; fi = widx[w];
                }
            }
            row[fi] = -INFINITY;
            adj[(size_t)n * NN + fi] = 1;
            adj[(size_t)fi * NN + n] = 1;
        }
        __syncthreads();
    }
}

// ------------------------------------- compact neighbor lists (ordered scan)
__global__ __launch_bounds__(256) void k_nbr(const unsigned char* __restrict__ adj,
                                             unsigned short* __restrict__ nbr_idx,
                                             int* __restrict__ nbr_cnt) {
    int n = blockIdx.x;
    int tid = threadIdx.x;
    __shared__ int cnts[256];
    int local[3]; int c = 0;
    #pragma unroll
    for (int i = 0; i < 3; ++i) {
        int m = 3 * tid + i;
        if (adj[(size_t)n * NN + m]) local[c++] = m;
    }
    cnts[tid] = c;
    __syncthreads();
    for (int off = 1; off < 256; off <<= 1) {
        int v = (tid >= off) ? cnts[tid - off] : 0;
        __syncthreads();
        cnts[tid] += v;
        __syncthreads();
    }
    int start = cnts[tid] - c;
    for (int i = 0; i < c; ++i)
        nbr_idx[(size_t)n * NN + start + i] = (unsigned short)local[i];
    if (tid == 255) nbr_cnt[n] = cnts[255];
}

// ---- fused: edge features + parallel edge MLP + sparse attention (per row)
__global__ __launch_bounds__(256) void k_edge_attn(
        const float* __restrict__ x,
        const double* __restrict__ nrm2_d,
        const double* __restrict__ nrm_d,
        const double* __restrict__ simd,
        const unsigned short* __restrict__ nbr_idx,
        const int* __restrict__ nbr_cnt,
        const float* __restrict__ e1_w, const float* __restrict__ e1_b,
        const float* __restrict__ e2_w, const float* __restrict__ e2_b,
        const float* __restrict__ gate_p,
        const float* __restrict__ q, const float* __restrict__ k,
        const float* __restrict__ v,
        unsigned short* __restrict__ ctxb) {
    int n = blockIdx.x;
    int tid = threadIdx.x;
    int w = tid >> 6, l = tid & 63;
    __shared__ unsigned short idxs[NN];
    __shared__ float w_sh[NHEAD][NN];
    __shared__ float ef2s[NN];
    __shared__ float ef3s[NN];
    __shared__ float qsh[NHEAD][HDIM];
    int cnt = nbr_cnt[n];
    for (int j = tid; j < cnt; j += 256) idxs[j] = nbr_idx[(size_t)n * NN + j];
    qsh[w][l] = q[((size_t)w * NN + n) * HDIM + l];
    __syncthreads();

    // ---- Phase A1: wave-parallel sab/mab per neighbor -> LDS
    float xa[4];
    #pragma unroll
    for (int i = 0; i < 4; ++i) xa[i] = x[(size_t)n * DD + l + 64 * i];

    for (int j = w; j < cnt; j += 4) {
        int m = idxs[j];
        float sab = 0.f, mab = 0.f;
        #pragma unroll
        for (int i = 0; i < 4; ++i) {
            float xb = x[(size_t)m * DD + l + 64 * i];
            float ad = fabsf(xa[i] - xb);
            sab += ad;
            mab = fmaxf(mab, ad);
        }
        #pragma unroll
        for (int off = 32; off > 0; off >>= 1) {
            sab += __shfl_xor(sab, off);
            mab = fmaxf(mab, __shfl_xor(mab, off));
        }
        if (l == 0) { ef2s[j] = sab * (1.f / 256.f); ef3s[j] = mab; }
    }
    __syncthreads();

    // ---- Phase A2: fully parallel edge MLP, thread -> (j = tid>>2, h = tid&3)
    double nrm2n = nrm2_d[n];
    double nrmn  = nrm_d[n];
    float gate = gate_p[0];
    for (int j0 = 0; j0 < cnt; j0 += 64) {
        int j = j0 + (tid >> 2);
        int hh = tid & 3;
        if (j < cnt) {
            int m = idxs[j];
            double s_d   = simd[(size_t)n * NN + m];
            double nrm2m = nrm2_d[m];
            double dotd  = s_d * nrmn * nrm_d[m];
            double l2sq  = fmax(nrm2n + nrm2m - 2.0 * dotd, 0.0);
            float ef0 = (float)s_d;
            float ef1 = (float)(sqrt(l2sq) * (1.0 / 16.0));
            float ef2 = ef2s[j];
            float ef3 = ef3s[j];
            float bb = e2_b[hh];
            #pragma unroll
            for (int jj = 0; jj < 8; ++jj) {
                float hv = e1_b[jj] + ef0 * e1_w[0 * 8 + jj] + ef1 * e1_w[1 * 8 + jj]
                         + ef2 * e1_w[2 * 8 + jj] + ef3 * e1_w[3 * 8 + jj];
                bb += fmaxf(hv, 0.f) * e2_w[jj * 4 + hh];
            }
            w_sh[hh][j] = gate * bb;
        }
    }
    __syncthreads();

    // ---- Phase B: logits + softmax (wave w owns head h=w)
    int h = w;
    float lmax = -INFINITY;
    for (int j = l; j < cnt; j += 64) {
        int m = idxs[j];
        const float4* kr = (const float4*)(k + ((size_t)h * NN + m) * HDIM);
        float dotv = 0.f;
        #pragma unroll
        for (int d4 = 0; d4 < HDIM / 4; ++d4) {
            float4 kv = kr[d4];
            dotv += qsh[h][4 * d4 + 0] * kv.x + qsh[h][4 * d4 + 1] * kv.y
                  + qsh[h][4 * d4 + 2] * kv.z + qsh[h][4 * d4 + 3] * kv.w;
        }
        w_sh[h][j] = dotv * 0.125f + w_sh[h][j];
        lmax = fmaxf(lmax, w_sh[h][j]);
    }
    #pragma unroll
    for (int off = 32; off > 0; off >>= 1)
        lmax = fmaxf(lmax, __shfl_xor(lmax, off));

    float lsum = 0.f;
    for (int j = l; j < cnt; j += 64) {
        float e = expf(w_sh[h][j] - lmax);
        w_sh[h][j] = e;
        lsum += e;
    }
    #pragma unroll
    for (int off = 32; off > 0; off >>= 1) lsum += __shfl_xor(lsum, off);
    float inv = 1.f / lsum;
    __syncthreads();

    // ---- PV: lane l = output dim, head h = w
    float acc = 0.f;
    #pragma unroll 4
    for (int j = 0; j < cnt; ++j)
        acc += w_sh[h][j] * v[((size_t)h * NN + idxs[j]) * HDIM + l];
    ctxb[(size_t)n * DD + h * HDIM + l] = f2bf(acc * inv);
}

// ---------------------- MFMA bf16 GEMM, 64x64 tile, 4 waves
// MODE 0: out fp32 = A@B+bias  MODE 1: += resid  MODE 2: qkv scatter
// MODE 3: outb bf16 = A@B+bias
template<int KD, int MODE, bool CONCAT>
__global__ __launch_bounds__(256) void k_gemm_mf(const unsigned short* __restrict__ A,
                                                 const unsigned short* __restrict__ A2,
                                                 const float* __restrict__ B,
                                                 const float* __restrict__ bias,
                                                 const float* __restrict__ resid,
                                                 float* __restrict__ out,
                                                 unsigned short* __restrict__ outb,
                                                 float* __restrict__ q,
                                                 float* __restrict__ k,
                                                 float* __restrict__ v,
                                                 int ncols) {
    __shared__ unsigned short As[64][40];
    __shared__ unsigned short Bs[64][40];
    int n0 = blockIdx.y * 64, c0 = blockIdx.x * 64;
    int tid = threadIdx.x;
    int wid = tid >> 6, lane = tid & 63;
    int wr = wid >> 1, wc = wid & 1;
    f32x4 zero = {0.f, 0.f, 0.f, 0.f};
    f32x4 acc[2][2];
    acc[0][0] = zero; acc[0][1] = zero; acc[1][0] = zero; acc[1][1] = zero;

    int s_arow = tid >> 2, s_ak = (tid & 3) * 8;
    int s_bk = tid >> 3,  s_bc = (tid & 7) * 8;
    int fr = lane & 15, fk = (lane >> 4) * 8, fg = lane >> 4;

    for (int k0 = 0; k0 < KD; k0 += 32) {
        const unsigned short* Asrc = A; int koff = k0;
        int lda = CONCAT ? 256 : KD;
        if (CONCAT && k0 >= 256) { Asrc = A2; koff = k0 - 256; }
        *(short8*)&As[s_arow][s_ak] =
            *(const short8*)&Asrc[(size_t)(n0 + s_arow) * lda + koff + s_ak];
        float4 b0 = *(const float4*)&B[(size_t)(k0 + s_bk) * ncols + c0 + s_bc];
        float4 b1 = *(const float4*)&B[(size_t)(k0 + s_bk) * ncols + c0 + s_bc + 4];
        Bs[s_bc + 0][s_bk] = f2bf(b0.x);
        Bs[s_bc + 1][s_bk] = f2bf(b0.y);
        Bs[s_bc + 2][s_bk] = f2bf(b0.z);
        Bs[s_bc + 3][s_bk] = f2bf(b0.w);
        Bs[s_bc + 4][s_bk] = f2bf(b1.x);
        Bs[s_bc + 5][s_bk] = f2bf(b1.y);
        Bs[s_bc + 6][s_bk] = f2bf(b1.z);
        Bs[s_bc + 7][s_bk] = f2bf(b1.w);
        __syncthreads();
        short8 af0 = *(const short8*)&As[wr * 32 + 0  + fr][fk];
        short8 af1 = *(const short8*)&As[wr * 32 + 16 + fr][fk];
        short8 bf0 = *(const short8*)&Bs[wc * 32 + 0  + fr][fk];
        short8 bf1 = *(const short8*)&Bs[wc * 32 + 16 + fr][fk];
        acc[0][0] = __builtin_amdgcn_mfma_f32_16x16x32_bf16(af0, bf0, acc[0][0], 0, 0, 0);
        acc[0][1] = __builtin_amdgcn_mfma_f32_16x16x32_bf16(af0, bf1, acc[0][1], 0, 0, 0);
        acc[1][0] = __builtin_amdgcn_mfma_f32_16x16x32_bf16(af1, bf0, acc[1][0], 0, 0, 0);
        acc[1][1] = __builtin_amdgcn_mfma_f32_16x16x32_bf16(af1, bf1, acc[1][1], 0, 0, 0);
        __syncthreads();
    }

    #pragma unroll
    for (int j = 0; j < 2; ++j) {
        int c = c0 + wc * 32 + j * 16 + fr;
        if (MODE == 2) {
            int hh = c / 192, rem = c % 192, hd = rem / 3, s = rem % 3;
            float* dst = (s == 0) ? q : (s == 1) ? k : v;
            float bb = bias[c];
            #pragma unroll
            for (int i = 0; i < 2; ++i)
                #pragma unroll
                for (int r = 0; r < 4; ++r) {
                    int n = n0 + wr * 32 + i * 16 + fg * 4 + r;
                    dst[((size_t)hh * NN + n) * HDIM + hd] = acc[i][j][r] + bb;
                }
        } else {
            float bb = bias[c];
            #pragma unroll
            for (int i = 0; i < 2; ++i)
                #pragma unroll
                for (int r = 0; r < 4; ++r) {
                    int n = n0 + wr * 32 + i * 16 + fg * 4 + r;
                    float val = acc[i][j][r] + bb;
                    if (MODE == 1) val += resid[(size_t)n * ncols + c];
                    if (MODE == 3) outb[(size_t)n * ncols + c] = f2bf(val);
                    else           out [(size_t)n * ncols + c] = val;
                }
        }
    }
}

// ------------------------------- LayerNorm + exact GELU -> bf16
__global__ __launch_bounds__(256) void k_ln_gelu(const float* __restrict__ y,
                                                 const float* __restrict__ g,
                                                 const float* __restrict__ b,
                                                 unsigned short* __restrict__ ybb) {
    int n = blockIdx.x;
    int tid = threadIdx.x;
    const float* row = y + (size_t)n * 512;
    __shared__ float red[256];
    float v0 = row[tid], v1 = row[tid + 256];

    red[tid] = v0 + v1; __syncthreads();
    for (int s = 128; s > 0; s >>= 1) {
        if (tid < s) red[tid] += red[tid + s];
        __syncthreads();
    }
    float mu = red[0] * (1.f / 512.f);
    __syncthreads();

    float d0 = v0 - mu, d1 = v1 - mu;
    red[tid] = d0 * d0 + d1 * d1; __syncthreads();
    for (int s = 128; s > 0; s >>= 1) {
        if (tid < s) red[tid] += red[tid + s];
        __syncthreads();
    }
    float var = red[0] * (1.f / 512.f);
    float rstd = 1.f / sqrtf(var + 1e-5f);

    float z0 = d0 * rstd * g[tid] + b[tid];
    float z1 = d1 * rstd * g[tid + 256] + b[tid + 256];
    float o0 = 0.5f * z0 * (1.f + erff(z0 * 0.70710678118654752f));
    float o1 = 0.5f * z1 * (1.f + erff(z1 * 0.70710678118654752f));
    ybb[(size_t)n * 512 + tid]       = f2bf(o0);
    ybb[(size_t)n * 512 + tid + 256] = f2bf(o1);
}

// --------------------------------------------------------------------- host
extern "C" void kernel_launch(void* const* d_in, const int* in_sizes, int n_in,
                              void* d_out, int out_size, void* d_ws, size_t ws_size,
                              hipStream_t stream) {
    const float* x       = (const float*)d_in[0];
    const float* Wqkv_w  = (const float*)d_in[1];
    const float* Wqkv_b  = (const float*)d_in[2];
    const float* out_w   = (const float*)d_in[3];
    const float* out_b   = (const float*)d_in[4];
    const float* ffn1_w  = (const float*)d_in[5];
    const float* ffn1_b  = (const float*)d_in[6];
    const float* ln_g    = (const float*)d_in[7];
    const float* ln_b    = (const float*)d_in[8];
    const float* ffn2_w  = (const float*)d_in[9];
    const float* ffn2_b  = (const float*)d_in[10];
    const float* e1_w    = (const float*)d_in[11];
    const float* e1_b    = (const float*)d_in[12];
    const float* e2_w    = (const float*)d_in[13];
    const float* e2_b    = (const float*)d_in[14];
    const float* gate    = (const float*)d_in[15];

    char* base = (char*)d_ws;
    double* simd   = (double*)base;            base += (size_t)NN * NN * 8;
    double* nrm2_d = (double*)base;            base += NN * 8;
    double* nrm_d  = (double*)base;            base += NN * 8;
    double* invn_d = (double*)base;            base += NN * 8;
    float* qb      = (float*)base;             base += (size_t)NN * DD * 4;
    float* kb      = (float*)base;             base += (size_t)NN * DD * 4;
    float* vb      = (float*)base;             base += (size_t)NN * DD * 4;
    float* yb      = (float*)base;             base += (size_t)NN * 512 * 4;
    int* nbr_cnt   = (int*)base;               base += NN * 4;
    unsigned short* nbr_idx = (unsigned short*)base; base += (size_t)NN * NN * 2;
    unsigned char* adj = (unsigned char*)base;  base += (size_t)NN * NN;
    unsigned short* xbf  = (unsigned short*)base; base += (size_t)NN * DD * 2;
    unsigned short* ctxb = (unsigned short*)base; base += (size_t)NN * DD * 2;
    unsigned short* msgb = (unsigned short*)base; base += (size_t)NN * DD * 2;
    unsigned short* ybb  = (unsigned short*)base; base += (size_t)NN * 512 * 2;

    hipMemsetAsync(adj, 0, (size_t)NN * NN, stream);

    k_norms<<<NN, 64, 0, stream>>>(x, nrm2_d, nrm_d, invn_d, xbf);

    k_sim<<<24 * 25 / 2, 256, 0, stream>>>(x, invn_d, simd);

    k_gemm_mf<DD, 2, false><<<dim3(12, 12), 256, 0, stream>>>(
        xbf, nullptr, Wqkv_w, Wqkv_b, nullptr, nullptr, nullptr, qb, kb, vb, 3 * DD);

    k_topk<<<NN, 256, 0, stream>>>(simd, adj);

    k_nbr<<<NN, 256, 0, stream>>>(adj, nbr_idx, nbr_cnt);

    k_edge_attn<<<NN, 256, 0, stream>>>(x, nrm2_d, nrm_d, simd, nbr_idx, nbr_cnt,
                                        e1_w, e1_b, e2_w, e2_b, gate,
                                        qb, kb, vb, ctxb);

    // msg = ctx @ out_w + out_b  (bf16 out)
    k_gemm_mf<DD, 3, false><<<dim3(4, 12), 256, 0, stream>>>(
        ctxb, nullptr, out_w, out_b, nullptr, nullptr, msgb, nullptr, nullptr, nullptr, DD);

    // y = [x, msg] @ ffn1_w + ffn1_b
    k_gemm_mf<512, 0, true><<<dim3(8, 12), 256, 0, stream>>>(
        xbf, msgb, ffn1_w, ffn1_b, nullptr, yb, nullptr, nullptr, nullptr, nullptr, 512);

    k_ln_gelu<<<NN, 256, 0, stream>>>(yb, ln_g, ln_b, ybb);

    // out = x + y @ ffn2_w + ffn2_b
    k_gemm_mf<512, 1, false><<<dim3(4, 12), 256, 0, stream>>>(
        ybb, nullptr, ffn2_w, ffn2_b, x, (float*)d_out, nullptr, nullptr, nullptr, nullptr, DD);
}